// Round 12
// baseline (389.264 us; speedup 1.0000x reference)
//
#include <hip/hip_runtime.h>
#include <hip/hip_bf16.h>

#define T_TOK 4096
#define HD 1024
#define ID 2048
#define NE 8

typedef __attribute__((ext_vector_type(8))) __bf16 bf16x8;
typedef __attribute__((ext_vector_type(4))) float f32x4;
typedef __attribute__((ext_vector_type(4))) unsigned int u32x4;
typedef __attribute__((ext_vector_type(2))) unsigned int u32x2;

#define AS1 __attribute__((address_space(1)))
#define AS3 __attribute__((address_space(3)))

#define WAITV(N) asm volatile("s_waitcnt vmcnt(" #N ")" ::: "memory")
#define BAR()    asm volatile("s_barrier" ::: "memory")
#define LGKM0()  { asm volatile("s_waitcnt lgkmcnt(0)" ::: "memory"); __builtin_amdgcn_sched_barrier(0); }

__device__ __forceinline__ unsigned short f2bf(float f) {
  __hip_bfloat16 h = __float2bfloat16(f);
  return __builtin_bit_cast(unsigned short, h);
}
__device__ __forceinline__ unsigned int pk2(float lo, float hi) {
  return (unsigned int)f2bf(lo) | ((unsigned int)f2bf(hi) << 16);
}
__device__ __forceinline__ float bflo(unsigned int u) { return __builtin_bit_cast(float, u << 16); }
__device__ __forceinline__ float bfhi(unsigned int u) { return __builtin_bit_cast(float, u & 0xffff0000u); }
__device__ __forceinline__ void gl16(const void* g, void* l) {
  __builtin_amdgcn_global_load_lds((const AS1 unsigned int*)g, (AS3 unsigned int*)l, 16, 0, 0);
}

// ---------------- routing ----------------
__global__ void k_zero(int* cnt) { if (threadIdx.x < 32) cnt[threadIdx.x] = 0; }

__global__ __launch_bounds__(256) void k_route(const float* __restrict__ x,
    const float* __restrict__ gw, const float* __restrict__ bias,
    int* __restrict__ cnt, int* __restrict__ tokens, float* __restrict__ wts,
    int* __restrict__ slotrec)
{
  const int lane = threadIdx.x & 63;
  const int t = blockIdx.x * 4 + (threadIdx.x >> 6);
  const float* xr = x + (size_t)t * HD + lane * 16;
  f32x4 xv[4];
  #pragma unroll
  for (int j = 0; j < 4; ++j) xv[j] = *(const f32x4*)(xr + j * 4);
  float sc[NE];
  #pragma unroll
  for (int e = 0; e < NE; ++e) {
    const float* gr = gw + e * HD + lane * 16;
    float a = 0.f;
    #pragma unroll
    for (int j = 0; j < 4; ++j) {
      f32x4 gv = *(const f32x4*)(gr + j * 4);
      a += xv[j][0]*gv[0] + xv[j][1]*gv[1] + xv[j][2]*gv[2] + xv[j][3]*gv[3];
    }
    #pragma unroll
    for (int off = 32; off > 0; off >>= 1) a += __shfl_xor(a, off);
    sc[e] = a;
  }
  int i1 = 0; float b1 = sc[0] + bias[0];
  #pragma unroll
  for (int e = 1; e < NE; ++e) { float be = sc[e] + bias[e]; if (be > b1) { b1 = be; i1 = e; } }
  int i2 = -1; float b2 = -3e38f;
  #pragma unroll
  for (int e = 0; e < NE; ++e) { if (e == i1) continue; float be = sc[e] + bias[e]; if (be > b2) { b2 = be; i2 = e; } }
  int a1 = 0; float r1 = sc[0];
  #pragma unroll
  for (int e = 1; e < NE; ++e) if (sc[e] > r1) { r1 = sc[e]; a1 = e; }
  float r2 = -3e38f;
  #pragma unroll
  for (int e = 0; e < NE; ++e) if (e != a1 && sc[e] > r2) r2 = sc[e];
  float w1 = 1.f / (1.f + __expf(-r1));
  float w2 = 1.f / (1.f + __expf(-r2));
  float s = w1 + w2; w1 /= s; w2 /= s;
  if (lane == 0) {
    int p = atomicAdd(&cnt[i1], 1); tokens[i1 * T_TOK + p] = t; wts[i1 * T_TOK + p] = w1;
    slotrec[t * 2] = (i1 << 16) | p;
    p = atomicAdd(&cnt[i2], 1);     tokens[i2 * T_TOK + p] = t; wts[i2 * T_TOK + p] = w2;
    slotrec[t * 2 + 1] = (i2 << 16) | p;
  }
}

__global__ void k_fin(const int* __restrict__ cnt, int* __restrict__ base, float* __restrict__ out)
{
  if (threadIdx.x == 0) {
    int b = 0, mx = 0;
    #pragma unroll
    for (int e = 0; e < NE; ++e) { base[e] = b; b += cnt[e]; if (cnt[e] > mx) mx = cnt[e]; }
    base[NE] = b;
    out[(size_t)T_TOK * HD] = (float)mx * (1.f / 1024.f) - 1.f;  // viol
  }
}

// ---------------- fused converts ----------------
__device__ __forceinline__ void tcvt_tile(const float* __restrict__ src, unsigned short* __restrict__ dst,
                                          int K, int N, int mode, int k0, int n0, unsigned short* tl)
{
  const int t = threadIdx.x;
  const int nc = (t & 15) * 4;
  #pragma unroll
  for (int it = 0; it < 4; ++it) {
    int kr = (t >> 4) + it * 16;
    f32x4 v = *(const f32x4*)&src[(size_t)(k0 + kr) * N + n0 + nc];
    #pragma unroll
    for (int j = 0; j < 4; ++j) {
      int n = nc + j;
      tl[n * 64 + (((kr >> 3) ^ (n & 7)) * 8) + (kr & 7)] = f2bf(v[j]);
    }
  }
  __syncthreads();
  #pragma unroll
  for (int it = 0; it < 2; ++it) {
    int idx = t + it * 256;
    int n = idx >> 3, kc8 = idx & 7;
    u32x4 v = *(const u32x4*)&tl[n * 64 + ((kc8 ^ (n & 7)) * 8)];
    int nn = n0 + n;
    int vrow = (mode == 0) ? nn : (((nn >> 5) << 6) + (nn & 31) + ((mode == 2) ? 32 : 0));
    *(u32x4*)&dst[(size_t)vrow * K + k0 + kc8 * 8] = v;
  }
}

__global__ __launch_bounds__(256) void k_conv(const float* __restrict__ x,
    const float* __restrict__ Wg, const float* __restrict__ Wu,
    const float* __restrict__ Sg, const float* __restrict__ Su,
    const float* __restrict__ Wd, const float* __restrict__ Sd,
    unsigned short* __restrict__ xb, unsigned short* __restrict__ Wgu, unsigned short* __restrict__ Sgu,
    unsigned short* __restrict__ WdT, unsigned short* __restrict__ SdT)
{
  __shared__ __attribute__((aligned(16))) unsigned short tl[64 * 64];
  int bid = blockIdx.x;
  if (bid < 2048) {
    size_t i = ((size_t)bid * 256 + threadIdx.x) * 8;
    f32x4 v0 = *(const f32x4*)(x + i), v1 = *(const f32x4*)(x + i + 4);
    u32x4 pk = { pk2(v0[0],v0[1]), pk2(v0[2],v0[3]), pk2(v1[0],v1[1]), pk2(v1[2],v1[3]) };
    *(u32x4*)&xb[i] = pk;
    return;
  }
  bid -= 2048;
  if (bid < 9216) {
    int z = bid >> 9, rem = bid & 511;
    int bx = rem & 31, by = rem >> 5;
    const float* src; unsigned short* dst; int mode;
    if (z < 8)        { src = Wg + (size_t)z * HD * ID;       dst = Wgu + (size_t)z * 4096 * 1024; mode = 1; }
    else if (z < 16)  { src = Wu + (size_t)(z - 8) * HD * ID; dst = Wgu + (size_t)(z - 8) * 4096 * 1024; mode = 2; }
    else if (z == 16) { src = Sg; dst = Sgu; mode = 1; }
    else              { src = Su; dst = Sgu; mode = 2; }
    tcvt_tile(src, dst, HD, ID, mode, by * 64, bx * 64, tl);
    return;
  }
  bid -= 9216;
  {
    int z = bid >> 9, rem = bid & 511;
    int bx = rem & 15, by = rem >> 4;
    const float* src = (z < 8) ? Wd + (size_t)z * ID * HD : Sd;
    unsigned short* dst = (z < 8) ? WdT + (size_t)z * ID * HD : SdT;
    tcvt_tile(src, dst, ID, HD, 0, by * 64, bx * 64, tl);
  }
}

// bijective chunked XCD mapping over the compacted active-tile list
__device__ __forceinline__ int chunked_vid(int bid, int total) {
  int xcd = bid & 7, idx = bid >> 3;
  int q = total >> 3, r = total & 7;
  int cap = (xcd < r) ? q + 1 : q;
  if (idx >= cap) return -1;
  int base = (xcd < r) ? xcd * (q + 1) : r * (q + 1) + (xcd - r) * q;
  return base + idx;
}

// ================= GEMM template: 256x256 tile, BK=32, 4 slots, depth-3, 1 barrier/tile =================
// LDS slot layout A/B: [256 rows][32 k] bf16, 64B rows; 16B chunk c of row r holds k-group c^((r>>1)&3).
// Staging: kgf = (tid&3)^((tid>>3)&3); gl16 j covers rows j*128 + tid>>2; dest = slot + j*8192B + w*1024B.
// Reads: frag row R, k-group lg -> chunk lg^((R>>1)&3); 2-way bank aliasing (free).

#define GEMM_DECL() \
  f32x4 acc[8][4]; \
  { const f32x4 z4 = {0.f,0.f,0.f,0.f}; \
    _Pragma("unroll") for (int i = 0; i < 8; ++i) _Pragma("unroll") for (int j = 0; j < 4; ++j) acc[i][j] = z4; } \
  const int lr = lane & 15, lg = lane >> 4; \
  const int wm = (w >> 2) * 128; \
  const int wn4 = (w & 3) * 64; \
  int abyte[8], bbyte[4]; \
  _Pragma("unroll") for (int am = 0; am < 8; ++am) { int rr = wm + am * 16 + lr;  abyte[am] = rr * 64 + ((lg ^ ((lr >> 1) & 3)) * 16); } \
  _Pragma("unroll") for (int bn = 0; bn < 4; ++bn) { int rr = wn4 + bn * 16 + lr; bbyte[bn] = rr * 64 + ((lg ^ ((lr >> 1) & 3)) * 16); } \
  bf16x8 af[8], bfr[4];

#define ST(tt_, s_) { \
  size_t kb = (size_t)(tt_) * 64; \
  gl16(asp0 + kb, &Abuf[s_][0    + w * 512]); \
  gl16(asp1 + kb, &Abuf[s_][4096 + w * 512]); \
  gl16(bsp0 + kb, &Bbuf[s_][0    + w * 512]); \
  gl16(bsp1 + kb, &Bbuf[s_][4096 + w * 512]); }

#define LD(s_) { \
  _Pragma("unroll") for (int am_ = 0; am_ < 8; ++am_) af[am_]  = *(const bf16x8*)((const char*)&Abuf[s_][0] + abyte[am_]); \
  _Pragma("unroll") for (int bn_ = 0; bn_ < 4; ++bn_) bfr[bn_] = *(const bf16x8*)((const char*)&Bbuf[s_][0] + bbyte[bn_]); }

#define MM() { __builtin_amdgcn_s_setprio(1); \
  _Pragma("unroll") for (int bn_ = 0; bn_ < 4; ++bn_) \
    _Pragma("unroll") for (int am_ = 0; am_ < 8; ++am_) \
      acc[am_][bn_] = __builtin_amdgcn_mfma_f32_16x16x32_bf16(af[am_], bfr[bn_], acc[am_][bn_], 0, 0, 0); \
  __builtin_amdgcn_s_setprio(0); }

// K-loop: NT=32 tiles of K=32. One barrier per tile.
#define KLOOP() { \
  ST(0, 0); ST(1, 1); ST(2, 2); \
  WAITV(8); BAR(); \
  for (int t = 0; t < 24; t += 4) { \
    ST(t + 3, 3); LD(0); LGKM0(); MM(); WAITV(8); BAR(); \
    ST(t + 4, 0); LD(1); LGKM0(); MM(); WAITV(8); BAR(); \
    ST(t + 5, 1); LD(2); LGKM0(); MM(); WAITV(8); BAR(); \
    ST(t + 6, 2); LD(3); LGKM0(); MM(); WAITV(8); BAR(); \
  } \
  /* tiles 24..27 stage 27..30; tile 28 stages 31; then drain */ \
  ST(27, 3); LD(0); LGKM0(); MM(); WAITV(8); BAR(); \
  ST(28, 0); LD(1); LGKM0(); MM(); WAITV(8); BAR(); \
  ST(29, 1); LD(2); LGKM0(); MM(); WAITV(8); BAR(); \
  ST(30, 2); LD(3); LGKM0(); MM(); WAITV(8); BAR(); \
  ST(31, 3); LD(0); LGKM0(); MM(); WAITV(8); BAR(); \
  LD(1); LGKM0(); MM(); WAITV(4); BAR(); \
  LD(2); LGKM0(); MM(); WAITV(0); BAR(); \
  LD(3); LGKM0(); MM(); }

// ================= GEMM1 =================
__global__ __launch_bounds__(512) void k_mlp1(
    const unsigned short* __restrict__ xb,
    const unsigned short* __restrict__ Wgu, const unsigned short* __restrict__ Sgu,
    const int* __restrict__ cnt, const int* __restrict__ base, const int* __restrict__ tokens,
    unsigned short* __restrict__ act)
{
  __shared__ __attribute__((aligned(16))) unsigned short Abuf[4][8192];
  __shared__ __attribute__((aligned(16))) unsigned short Bbuf[4][8192];

  int total = 0;
  #pragma unroll
  for (int ee = 0; ee < 9; ++ee) {
    int c = (ee == 8) ? T_TOK : cnt[ee];
    total += ((c + 255) >> 8) * 16;
  }
  const int vid = chunked_vid(blockIdx.x, total);
  if (vid < 0) return;
  int e = -1, loc = vid, amv = 1;
  #pragma unroll
  for (int ee = 0; ee < 9; ++ee) {
    int c = (ee == 8) ? T_TOK : cnt[ee];
    int a = (c + 255) >> 8;
    int sz = a * 16;
    if (e < 0) { if (loc < sz) { e = ee; amv = a; } else loc -= sz; }
  }
  int nx = 0; while (loc >= amv) { loc -= amv; ++nx; }
  const int my = loc;

  const int cntE = (e == NE) ? T_TOK : cnt[e];
  const int m0 = my * 256;
  const int n0 = nx * 256;
  const unsigned short* Bsrc = (e == NE) ? Sgu : Wgu + (size_t)e * 4096 * 1024;
  const int rowbase = (e == NE) ? 2 * T_TOK : base[e];
  const int tid = threadIdx.x, lane = tid & 63, w = tid >> 6;
  const int kgf = (tid & 3) ^ ((tid >> 3) & 3);
  const int srow = tid >> 2;                 // 0..127

  const char *asp0, *asp1, *bsp0, *bsp1;
  {
    int r0 = min(m0 + srow, cntE - 1);
    int r1 = min(m0 + 128 + srow, cntE - 1);
    int t0 = (e == NE) ? r0 : tokens[e * T_TOK + r0];
    int t1 = (e == NE) ? r1 : tokens[e * T_TOK + r1];
    asp0 = (const char*)(xb + (size_t)t0 * HD + kgf * 8);
    asp1 = (const char*)(xb + (size_t)t1 * HD + kgf * 8);
    bsp0 = (const char*)(Bsrc + (size_t)(n0 + srow) * HD + kgf * 8);
    bsp1 = (const char*)(Bsrc + (size_t)(n0 + 128 + srow) * HD + kgf * 8);
  }

  GEMM_DECL();
  KLOOP();

  // epilogue: gate frags (bn 0,1) pair with up frags (bn 2,3)
  const int colbase = ((n0 + wn4) >> 1);
  #pragma unroll
  for (int am = 0; am < 8; ++am) {
    const int rloc = wm + am * 16 + lg * 4;
    #pragma unroll
    for (int p = 0; p < 2; ++p) {
      f32x4 gv = acc[am][p], uv = acc[am][p + 2];
      int col = colbase + p * 16 + lr;
      #pragma unroll
      for (int q = 0; q < 4; ++q) {
        int r = rloc + q;
        if (m0 + r < cntE) {
          float g_ = gv[q], u_ = uv[q];
          act[(size_t)(rowbase + m0 + r) * ID + col] = f2bf((g_ / (1.f + __expf(-g_))) * u_);
        }
      }
    }
  }
}

// ================= GEMM2: split-K=2 =================
__global__ __launch_bounds__(512) void k_mlp2(
    const unsigned short* __restrict__ act,
    const unsigned short* __restrict__ WdT, const unsigned short* __restrict__ SdT,
    const int* __restrict__ cnt, const int* __restrict__ base,
    unsigned short* __restrict__ dn0, unsigned short* __restrict__ dn1)
{
  __shared__ __attribute__((aligned(16))) unsigned short Abuf[4][8192];
  __shared__ __attribute__((aligned(16))) unsigned short Bbuf[4][8192];

  int total = 0;
  #pragma unroll
  for (int ee = 0; ee < 9; ++ee) {
    int c = (ee == 8) ? T_TOK : cnt[ee];
    total += ((c + 255) >> 8) * 8;
  }
  const int vid = chunked_vid(blockIdx.x, total);
  if (vid < 0) return;
  int e = -1, loc = vid, amv = 1;
  #pragma unroll
  for (int ee = 0; ee < 9; ++ee) {
    int c = (ee == 8) ? T_TOK : cnt[ee];
    int a = (c + 255) >> 8;
    int sz = a * 8;
    if (e < 0) { if (loc < sz) { e = ee; amv = a; } else loc -= sz; }
  }
  int nxkh = 0; while (loc >= amv) { loc -= amv; ++nxkh; }
  const int my = loc;
  const int nx = nxkh >> 1, kh = nxkh & 1;

  const int cntE = (e == NE) ? T_TOK : cnt[e];
  const int m0 = my * 256;
  const int n0 = nx * 256;
  const unsigned short* Bsrc = (e == NE) ? SdT : WdT + (size_t)e * ID * HD;
  const int rowbase = (e == NE) ? 2 * T_TOK : base[e];
  const int koff = kh * 1024;
  const int tid = threadIdx.x, lane = tid & 63, w = tid >> 6;
  const int kgf = (tid & 3) ^ ((tid >> 3) & 3);
  const int srow = tid >> 2;

  const char *asp0, *asp1, *bsp0, *bsp1;
  {
    int r0 = rowbase + min(m0 + srow, cntE - 1);
    int r1 = rowbase + min(m0 + 128 + srow, cntE - 1);
    asp0 = (const char*)(act + (size_t)r0 * ID + koff + kgf * 8);
    asp1 = (const char*)(act + (size_t)r1 * ID + koff + kgf * 8);
    bsp0 = (const char*)(Bsrc + (size_t)(n0 + srow) * ID + koff + kgf * 8);
    bsp1 = (const char*)(Bsrc + (size_t)(n0 + 128 + srow) * ID + koff + kgf * 8);
  }

  GEMM_DECL();
  KLOOP();

  unsigned short* dnp = kh ? dn1 : dn0;
  #pragma unroll
  for (int am = 0; am < 8; ++am) {
    const int rloc = wm + am * 16 + lg * 4;
    #pragma unroll
    for (int bn = 0; bn < 4; ++bn) {
      f32x4 av = acc[am][bn];
      int col = n0 + wn4 + bn * 16 + lr;
      #pragma unroll
      for (int q = 0; q < 4; ++q) {
        int r = rloc + q;
        if (m0 + r < cntE)
          dnp[(size_t)(rowbase + m0 + r) * HD + col] = f2bf(av[q]);
      }
    }
  }
}

// ---------------- combine ----------------
__global__ __launch_bounds__(256) void k_comb(const unsigned short* __restrict__ dn0,
    const unsigned short* __restrict__ dn1,
    const int* __restrict__ base, const int* __restrict__ slotrec,
    const float* __restrict__ wts, float* __restrict__ out)
{
  const int t = blockIdx.x;
  const int c = threadIdx.x * 4;
  int r0 = slotrec[t * 2], r1 = slotrec[t * 2 + 1];
  int e0 = r0 >> 16, p0 = r0 & 0xffff;
  int e1 = r1 >> 16, p1 = r1 & 0xffff;
  size_t s0 = (size_t)(base[e0] + p0) * HD + c;
  size_t s1 = (size_t)(base[e1] + p1) * HD + c;
  size_t sh = (size_t)(2 * T_TOK + t) * HD + c;
  float w0 = wts[e0 * T_TOK + p0], w1 = wts[e1 * T_TOK + p1];
  u32x2 vs0 = *(const u32x2*)&dn0[sh], vs1 = *(const u32x2*)&dn1[sh];
  u32x2 va0 = *(const u32x2*)&dn0[s0], va1 = *(const u32x2*)&dn1[s0];
  u32x2 vb0 = *(const u32x2*)&dn0[s1], vb1 = *(const u32x2*)&dn1[s1];
  f32x4 o;
  o[0] = (bflo(vs0[0]) + bflo(vs1[0])) + w0 * (bflo(va0[0]) + bflo(va1[0])) + w1 * (bflo(vb0[0]) + bflo(vb1[0]));
  o[1] = (bfhi(vs0[0]) + bfhi(vs1[0])) + w0 * (bfhi(va0[0]) + bfhi(va1[0])) + w1 * (bfhi(vb0[0]) + bfhi(vb1[0]));
  o[2] = (bflo(vs0[1]) + bflo(vs1[1])) + w0 * (bflo(va0[1]) + bflo(va1[1])) + w1 * (bflo(vb0[1]) + bflo(vb1[1]));
  o[3] = (bfhi(vs0[1]) + bfhi(vs1[1])) + w0 * (bfhi(va0[1]) + bfhi(va1[1])) + w1 * (bfhi(vb0[1]) + bfhi(vb1[1]));
  *(f32x4*)&out[(size_t)t * HD + c] = o;
}

extern "C" void kernel_launch(void* const* d_in, const int* in_sizes, int n_in,
                              void* d_out, int out_size, void* d_ws, size_t ws_size,
                              hipStream_t stream)
{
  const float* x    = (const float*)d_in[0];
  const float* gw   = (const float*)d_in[1];
  const float* bias = (const float*)d_in[2];
  const float* Wg   = (const float*)d_in[3];
  const float* Wu   = (const float*)d_in[4];
  const float* Wd   = (const float*)d_in[5];
  const float* Sg   = (const float*)d_in[6];
  const float* Su   = (const float*)d_in[7];
  const float* Sd   = (const float*)d_in[8];
  float* out = (float*)d_out;
  char* ws = (char*)d_ws;

  int*   cnt     = (int*)ws;
  int*   base    = cnt + 16;
  int*   tokens  = (int*)(ws + 512);
  float* wts     = (float*)(ws + 512 + (NE * T_TOK * 4));
  int*   slotrec = (int*)(ws + 512 + 2 * (NE * T_TOK * 4));

  const size_t MB = (size_t)1 << 20;
  unsigned short* xbf = (unsigned short*)(ws + 1 * MB);    // 8 MB
  unsigned short* WdT = (unsigned short*)(ws + 9 * MB);    // 32 MB
  unsigned short* SdT = (unsigned short*)(ws + 41 * MB);   // 4 MB
  unsigned short* Wgu = (unsigned short*)(ws + 45 * MB);   // 64 MB (dead after mlp1)
  unsigned short* Sgu = (unsigned short*)(ws + 109 * MB);  // 8 MB (dead after mlp1)
  unsigned short* actb = (unsigned short*)(ws + 117 * MB); // 48 MB
  unsigned short* dn0 = (unsigned short*)(ws + 45 * MB);   // 24 MB, overlays Wgu
  unsigned short* dn1 = (unsigned short*)(ws + 69 * MB);   // 24 MB, overlays Wgu

  k_zero<<<dim3(1), dim3(64), 0, stream>>>(cnt);
  k_route<<<dim3(T_TOK / 4), dim3(256), 0, stream>>>(x, gw, bias, cnt, tokens, wts, slotrec);
  k_fin<<<dim3(1), dim3(64), 0, stream>>>(cnt, base, out);
  k_conv<<<dim3(2048 + 9216 + 4608), dim3(256), 0, stream>>>(x, Wg, Wu, Sg, Su, Wd, Sd,
                                                             xbf, Wgu, Sgu, WdT, SdT);
  k_mlp1<<<dim3(2304), dim3(512), 0, stream>>>(xbf, Wgu, Sgu, cnt, base, tokens, actb);
  k_mlp2<<<dim3(1152), dim3(512), 0, stream>>>(actb, WdT, SdT, cnt, base, dn0, dn1);
  k_comb<<<dim3(T_TOK), dim3(256), 0, stream>>>(dn0, dn1, base, slotrec, wts, out);
}

// Round 13
// 368.238 us; speedup vs baseline: 1.0571x; 1.0571x over previous
//
#include <hip/hip_runtime.h>
#include <hip/hip_bf16.h>

#define T_TOK 4096
#define HD 1024
#define ID 2048
#define NE 8

typedef __attribute__((ext_vector_type(8))) __bf16 bf16x8;
typedef __attribute__((ext_vector_type(4))) float f32x4;
typedef __attribute__((ext_vector_type(4))) unsigned int u32x4;
typedef __attribute__((ext_vector_type(2))) unsigned int u32x2;

#define AS1 __attribute__((address_space(1)))
#define AS3 __attribute__((address_space(3)))

#define WAITV(N) asm volatile("s_waitcnt vmcnt(" #N ")" ::: "memory")
#define BAR()    asm volatile("s_barrier" ::: "memory")
#define LGKM0()  { asm volatile("s_waitcnt lgkmcnt(0)" ::: "memory"); __builtin_amdgcn_sched_barrier(0); }

__device__ __forceinline__ unsigned short f2bf(float f) {
  __hip_bfloat16 h = __float2bfloat16(f);
  return __builtin_bit_cast(unsigned short, h);
}
__device__ __forceinline__ unsigned int pk2(float lo, float hi) {
  return (unsigned int)f2bf(lo) | ((unsigned int)f2bf(hi) << 16);
}
__device__ __forceinline__ float bflo(unsigned int u) { return __builtin_bit_cast(float, u << 16); }
__device__ __forceinline__ float bfhi(unsigned int u) { return __builtin_bit_cast(float, u & 0xffff0000u); }
__device__ __forceinline__ void gl16(const void* g, void* l) {
  __builtin_amdgcn_global_load_lds((const AS1 unsigned int*)g, (AS3 unsigned int*)l, 16, 0, 0);
}

// ---------------- routing ----------------
__global__ void k_zero(int* cnt) { if (threadIdx.x < 32) cnt[threadIdx.x] = 0; }

__device__ __forceinline__ void route_body(int rbid, const float* __restrict__ x,
    const float* __restrict__ gw, const float* __restrict__ bias,
    int* __restrict__ cnt, int* __restrict__ tokens, float* __restrict__ wts,
    int* __restrict__ slotrec)
{
  const int lane = threadIdx.x & 63;
  const int t = rbid * 4 + (threadIdx.x >> 6);
  const float* xr = x + (size_t)t * HD + lane * 16;
  f32x4 xv[4];
  #pragma unroll
  for (int j = 0; j < 4; ++j) xv[j] = *(const f32x4*)(xr + j * 4);
  float sc[NE];
  #pragma unroll
  for (int e = 0; e < NE; ++e) {
    const float* gr = gw + e * HD + lane * 16;
    float a = 0.f;
    #pragma unroll
    for (int j = 0; j < 4; ++j) {
      f32x4 gv = *(const f32x4*)(gr + j * 4);
      a += xv[j][0]*gv[0] + xv[j][1]*gv[1] + xv[j][2]*gv[2] + xv[j][3]*gv[3];
    }
    #pragma unroll
    for (int off = 32; off > 0; off >>= 1) a += __shfl_xor(a, off);
    sc[e] = a;
  }
  int i1 = 0; float b1 = sc[0] + bias[0];
  #pragma unroll
  for (int e = 1; e < NE; ++e) { float be = sc[e] + bias[e]; if (be > b1) { b1 = be; i1 = e; } }
  int i2 = -1; float b2 = -3e38f;
  #pragma unroll
  for (int e = 0; e < NE; ++e) { if (e == i1) continue; float be = sc[e] + bias[e]; if (be > b2) { b2 = be; i2 = e; } }
  int a1 = 0; float r1 = sc[0];
  #pragma unroll
  for (int e = 1; e < NE; ++e) if (sc[e] > r1) { r1 = sc[e]; a1 = e; }
  float r2 = -3e38f;
  #pragma unroll
  for (int e = 0; e < NE; ++e) if (e != a1 && sc[e] > r2) r2 = sc[e];
  float w1 = 1.f / (1.f + __expf(-r1));
  float w2 = 1.f / (1.f + __expf(-r2));
  float s = w1 + w2; w1 /= s; w2 /= s;
  if (lane == 0) {
    int p = atomicAdd(&cnt[i1], 1); tokens[i1 * T_TOK + p] = t; wts[i1 * T_TOK + p] = w1;
    slotrec[t * 2] = (i1 << 16) | p;
    p = atomicAdd(&cnt[i2], 1);     tokens[i2 * T_TOK + p] = t; wts[i2 * T_TOK + p] = w2;
    slotrec[t * 2 + 1] = (i2 << 16) | p;
  }
}

__global__ void k_fin(const int* __restrict__ cnt, int* __restrict__ base, float* __restrict__ out)
{
  if (threadIdx.x == 0) {
    int b = 0, mx = 0;
    #pragma unroll
    for (int e = 0; e < NE; ++e) { base[e] = b; b += cnt[e]; if (cnt[e] > mx) mx = cnt[e]; }
    base[NE] = b;
    out[(size_t)T_TOK * HD] = (float)mx * (1.f / 1024.f) - 1.f;  // viol
  }
}

// ---------------- fused route + converts ----------------
__device__ __forceinline__ void tcvt_tile(const float* __restrict__ src, unsigned short* __restrict__ dst,
                                          int K, int N, int mode, int k0, int n0, unsigned short* tl)
{
  const int t = threadIdx.x;
  const int nc = (t & 15) * 4;
  #pragma unroll
  for (int it = 0; it < 4; ++it) {
    int kr = (t >> 4) + it * 16;
    f32x4 v = *(const f32x4*)&src[(size_t)(k0 + kr) * N + n0 + nc];
    #pragma unroll
    for (int j = 0; j < 4; ++j) {
      int n = nc + j;
      tl[n * 64 + (((kr >> 3) ^ (n & 7)) * 8) + (kr & 7)] = f2bf(v[j]);
    }
  }
  __syncthreads();
  #pragma unroll
  for (int it = 0; it < 2; ++it) {
    int idx = t + it * 256;
    int n = idx >> 3, kc8 = idx & 7;
    u32x4 v = *(const u32x4*)&tl[n * 64 + ((kc8 ^ (n & 7)) * 8)];
    int nn = n0 + n;
    int vrow = (mode == 0) ? nn : (((nn >> 5) << 6) + (nn & 31) + ((mode == 2) ? 32 : 0));
    *(u32x4*)&dst[(size_t)vrow * K + k0 + kc8 * 8] = v;
  }
}

// blocks 0..1023: route; 1024..3071: x cvt; 3072..12287: Wg/Wu/Sg/Su; 12288..16895: Wd/Sd
__global__ __launch_bounds__(256) void k_conv(const float* __restrict__ x,
    const float* __restrict__ gw, const float* __restrict__ bias,
    const float* __restrict__ Wg, const float* __restrict__ Wu,
    const float* __restrict__ Sg, const float* __restrict__ Su,
    const float* __restrict__ Wd, const float* __restrict__ Sd,
    unsigned short* __restrict__ xb, unsigned short* __restrict__ Wgu, unsigned short* __restrict__ Sgu,
    unsigned short* __restrict__ WdT, unsigned short* __restrict__ SdT,
    int* __restrict__ cnt, int* __restrict__ tokens, float* __restrict__ wts, int* __restrict__ slotrec)
{
  __shared__ __attribute__((aligned(16))) unsigned short tl[64 * 64];
  int bid = blockIdx.x;
  if (bid < 1024) {
    route_body(bid, x, gw, bias, cnt, tokens, wts, slotrec);
    return;
  }
  bid -= 1024;
  if (bid < 2048) {
    size_t i = ((size_t)bid * 256 + threadIdx.x) * 8;
    f32x4 v0 = *(const f32x4*)(x + i), v1 = *(const f32x4*)(x + i + 4);
    u32x4 pk = { pk2(v0[0],v0[1]), pk2(v0[2],v0[3]), pk2(v1[0],v1[1]), pk2(v1[2],v1[3]) };
    *(u32x4*)&xb[i] = pk;
    return;
  }
  bid -= 2048;
  if (bid < 9216) {
    int z = bid >> 9, rem = bid & 511;
    int bx = rem & 31, by = rem >> 5;
    const float* src; unsigned short* dst; int mode;
    if (z < 8)        { src = Wg + (size_t)z * HD * ID;       dst = Wgu + (size_t)z * 4096 * 1024; mode = 1; }
    else if (z < 16)  { src = Wu + (size_t)(z - 8) * HD * ID; dst = Wgu + (size_t)(z - 8) * 4096 * 1024; mode = 2; }
    else if (z == 16) { src = Sg; dst = Sgu; mode = 1; }
    else              { src = Su; dst = Sgu; mode = 2; }
    tcvt_tile(src, dst, HD, ID, mode, by * 64, bx * 64, tl);
    return;
  }
  bid -= 9216;
  {
    int z = bid >> 9, rem = bid & 511;
    int bx = rem & 15, by = rem >> 4;
    const float* src = (z < 8) ? Wd + (size_t)z * ID * HD : Sd;
    unsigned short* dst = (z < 8) ? WdT + (size_t)z * ID * HD : SdT;
    tcvt_tile(src, dst, ID, HD, 0, by * 64, bx * 64, tl);
  }
}

// bijective chunked XCD mapping over the compacted active-tile list
__device__ __forceinline__ int chunked_vid(int bid, int total) {
  int xcd = bid & 7, idx = bid >> 3;
  int q = total >> 3, r = total & 7;
  int cap = (xcd < r) ? q + 1 : q;
  if (idx >= cap) return -1;
  int base = (xcd < r) ? xcd * (q + 1) : r * (q + 1) + (xcd - r) * q;
  return base + idx;
}

// ================= GEMM1: 256x256 virtual (gate|up interleaved), fat 4-phase =================
__global__ __launch_bounds__(512, 2) void k_mlp1(
    const unsigned short* __restrict__ xb,
    const unsigned short* __restrict__ Wgu, const unsigned short* __restrict__ Sgu,
    const int* __restrict__ cnt, const int* __restrict__ base, const int* __restrict__ tokens,
    unsigned short* __restrict__ act)
{
  __shared__ __attribute__((aligned(16))) unsigned short Abuf[2][16384];
  __shared__ __attribute__((aligned(16))) unsigned short Bbuf[2][16384];

  // compacted active-tile list: vid = pref_e + nx*am_e + my (my fastest -> B-panel adjacency)
  int total = 0;
  #pragma unroll
  for (int ee = 0; ee < 9; ++ee) {
    int c = (ee == 8) ? T_TOK : cnt[ee];
    total += ((c + 255) >> 8) * 16;
  }
  const int vid = chunked_vid(blockIdx.x, total);
  if (vid < 0) return;
  int e = -1, loc = vid, amv = 1;
  #pragma unroll
  for (int ee = 0; ee < 9; ++ee) {
    int c = (ee == 8) ? T_TOK : cnt[ee];
    int a = (c + 255) >> 8;
    int sz = a * 16;
    if (e < 0) { if (loc < sz) { e = ee; amv = a; } else loc -= sz; }
  }
  int nx = 0; while (loc >= amv) { loc -= amv; ++nx; }
  const int my = loc;

  const int cntE = (e == NE) ? T_TOK : cnt[e];
  const int m0 = my * 256;
  const int n0 = nx * 256;
  const unsigned short* Bsrc = (e == NE) ? Sgu : Wgu + (size_t)e * 4096 * 1024;
  const int rowbase = (e == NE) ? 2 * T_TOK : base[e];
  const int tid = threadIdx.x, lane = tid & 63, w = tid >> 6;
  const int srow = tid >> 3;
  const int kgf = (tid & 7) ^ (srow & 7);

  const unsigned short* asrc[4]; const unsigned short* bsrc[4];
  #pragma unroll
  for (int u = 0; u < 4; ++u) {
    int r = u * 64 + srow;
    int rl = min(m0 + r, cntE - 1);
    int tok = (e == NE) ? rl : tokens[e * T_TOK + rl];
    asrc[u] = xb + (size_t)tok * HD + kgf * 8;
    bsrc[u] = Bsrc + (size_t)(n0 + r) * HD + kgf * 8;
  }

  f32x4 acc[8][4];
  const f32x4 z4 = {0.f, 0.f, 0.f, 0.f};
  #pragma unroll
  for (int i = 0; i < 8; ++i)
    #pragma unroll
    for (int j = 0; j < 4; ++j) acc[i][j] = z4;

  const int lr = lane & 15, lg = lane >> 4;
  const int wm = (w >> 2) * 128;
  const int wn4 = (w & 3) * 64;
  const int ck0 = (lg ^ (lr & 7)) * 16;
  const int arow0 = (wm + lr) * 128;
  const int brow0 = (wn4 + lr) * 128;

  bf16x8 af[4][2], bf[2][2][2];

  #define SA1(t_, h_, s_) { \
    gl16(asrc[(h_)*2+0] + (t_)*64, &Abuf[s_][(h_)*8192 + 0    + w*512]); \
    gl16(asrc[(h_)*2+1] + (t_)*64, &Abuf[s_][(h_)*8192 + 4096 + w*512]); }
  #define SB1(t_, h_, s_) { \
    gl16(bsrc[(h_)*2+0] + (t_)*64, &Bbuf[s_][(h_)*8192 + 0    + w*512]); \
    gl16(bsrc[(h_)*2+1] + (t_)*64, &Bbuf[s_][(h_)*8192 + 4096 + w*512]); }
  #define LDA1(s_, mh_) { _Pragma("unroll") for (int am_ = 0; am_ < 4; ++am_) { \
    af[am_][0] = *(const bf16x8*)((const char*)&Abuf[s_][0] + arow0 + (mh_)*8192 + am_*2048 + ck0); \
    af[am_][1] = *(const bf16x8*)((const char*)&Abuf[s_][0] + arow0 + (mh_)*8192 + am_*2048 + (ck0^64)); } }
  #define LDB1(s_, nh_) { _Pragma("unroll") for (int bn_ = 0; bn_ < 2; ++bn_) { \
    bf[nh_][bn_][0] = *(const bf16x8*)((const char*)&Bbuf[s_][0] + brow0 + (nh_)*4096 + bn_*2048 + ck0); \
    bf[nh_][bn_][1] = *(const bf16x8*)((const char*)&Bbuf[s_][0] + brow0 + (nh_)*4096 + bn_*2048 + (ck0^64)); } }
  #define MM1(mh_, nh_) { __builtin_amdgcn_s_setprio(1); \
    _Pragma("unroll") for (int bn_ = 0; bn_ < 2; ++bn_) \
      _Pragma("unroll") for (int am_ = 0; am_ < 4; ++am_) { \
        acc[(mh_)*4+am_][(nh_)*2+bn_] = __builtin_amdgcn_mfma_f32_16x16x32_bf16(af[am_][0], bf[nh_][bn_][0], acc[(mh_)*4+am_][(nh_)*2+bn_], 0,0,0); \
        acc[(mh_)*4+am_][(nh_)*2+bn_] = __builtin_amdgcn_mfma_f32_16x16x32_bf16(af[am_][1], bf[nh_][bn_][1], acc[(mh_)*4+am_][(nh_)*2+bn_], 0,0,0); } \
    __builtin_amdgcn_s_setprio(0); }

  const int NT1 = 16;
  SA1(0, 0, 0); SA1(0, 1, 0); SB1(0, 0, 0); SB1(0, 1, 0);
  SB1(1, 0, 1); SB1(1, 1, 1);
  WAITV(4);
  BAR();

  #define TILE1(t_, s_, o_) { \
    LDA1(s_, 0); LDB1(s_, 0); LDB1(s_, 1); \
    if ((t_)+1 < NT1) { SA1((t_)+1, 0, o_); SA1((t_)+1, 1, o_); } \
    BAR(); LGKM0(); MM1(0, 0); MM1(0, 1); BAR(); \
    LDA1(s_, 1); \
    if ((t_)+2 < NT1) { SB1((t_)+2, 0, s_); SB1((t_)+2, 1, s_); } \
    BAR(); LGKM0(); MM1(1, 1); MM1(1, 0); \
    if ((t_)+2 < NT1) { WAITV(4); } else { WAITV(0); } \
    BAR(); }

  for (int t = 0; t < NT1; t += 2) {
    TILE1(t, 0, 1);
    TILE1(t + 1, 1, 0);
  }
  #undef TILE1

  const int colbase = ((n0 + wn4) >> 1);
  #pragma unroll
  for (int mf = 0; mf < 8; ++mf) {
    const int rloc = wm + (mf >> 2) * 64 + (mf & 3) * 16 + lg * 4;
    #pragma unroll
    for (int p = 0; p < 2; ++p) {
      f32x4 gv = acc[mf][p], uv = acc[mf][p + 2];
      int col = colbase + p * 16 + lr;
      #pragma unroll
      for (int q = 0; q < 4; ++q) {
        int r = rloc + q;
        if (m0 + r < cntE) {
          float g_ = gv[q], u_ = uv[q];
          act[(size_t)(rowbase + m0 + r) * ID + col] = f2bf((g_ / (1.f + __expf(-g_))) * u_);
        }
      }
    }
  }
}

// ================= GEMM2: 256x256, split-K=2, fat 4-phase =================
__global__ __launch_bounds__(512, 2) void k_mlp2(
    const unsigned short* __restrict__ act,
    const unsigned short* __restrict__ WdT, const unsigned short* __restrict__ SdT,
    const int* __restrict__ cnt, const int* __restrict__ base,
    unsigned short* __restrict__ dn0, unsigned short* __restrict__ dn1)
{
  __shared__ __attribute__((aligned(16))) unsigned short Abuf[2][16384];
  __shared__ __attribute__((aligned(16))) unsigned short Bbuf[2][16384];

  // compacted active-tile list: vid = pref_e + (nx*2+kh)*am_e + my
  int total = 0;
  #pragma unroll
  for (int ee = 0; ee < 9; ++ee) {
    int c = (ee == 8) ? T_TOK : cnt[ee];
    total += ((c + 255) >> 8) * 8;
  }
  const int vid = chunked_vid(blockIdx.x, total);
  if (vid < 0) return;
  int e = -1, loc = vid, amv = 1;
  #pragma unroll
  for (int ee = 0; ee < 9; ++ee) {
    int c = (ee == 8) ? T_TOK : cnt[ee];
    int a = (c + 255) >> 8;
    int sz = a * 8;
    if (e < 0) { if (loc < sz) { e = ee; amv = a; } else loc -= sz; }
  }
  int nxkh = 0; while (loc >= amv) { loc -= amv; ++nxkh; }
  const int my = loc;
  const int nx = nxkh >> 1, kh = nxkh & 1;

  const int cntE = (e == NE) ? T_TOK : cnt[e];
  const int m0 = my * 256;
  const int n0 = nx * 256;
  const unsigned short* Bsrc = (e == NE) ? SdT : WdT + (size_t)e * ID * HD;
  const int rowbase = (e == NE) ? 2 * T_TOK : base[e];
  const int koff = kh * 1024;
  const int tid = threadIdx.x, lane = tid & 63, w = tid >> 6;
  const int srow = tid >> 3;
  const int kgf = (tid & 7) ^ (srow & 7);

  const unsigned short* asrc[4]; const unsigned short* bsrc[4];
  #pragma unroll
  for (int u = 0; u < 4; ++u) {
    int r = u * 64 + srow;
    int rl = rowbase + min(m0 + r, cntE - 1);
    asrc[u] = act + (size_t)rl * ID + koff + kgf * 8;
    bsrc[u] = Bsrc + (size_t)(n0 + r) * ID + koff + kgf * 8;
  }

  f32x4 acc[8][4];
  const f32x4 z4 = {0.f, 0.f, 0.f, 0.f};
  #pragma unroll
  for (int i = 0; i < 8; ++i)
    #pragma unroll
    for (int j = 0; j < 4; ++j) acc[i][j] = z4;

  const int lr = lane & 15, lg = lane >> 4;
  const int wm = (w >> 2) * 128;
  const int wn4 = (w & 3) * 64;
  const int ck0 = (lg ^ (lr & 7)) * 16;
  const int arow0 = (wm + lr) * 128;
  const int brow0 = (wn4 + lr) * 128;

  bf16x8 af[4][2], bf[2][2][2];

  #define SA2(t_, h_, s_) { \
    gl16(asrc[(h_)*2+0] + (t_)*64, &Abuf[s_][(h_)*8192 + 0    + w*512]); \
    gl16(asrc[(h_)*2+1] + (t_)*64, &Abuf[s_][(h_)*8192 + 4096 + w*512]); }
  #define SB2(t_, h_, s_) { \
    gl16(bsrc[(h_)*2+0] + (t_)*64, &Bbuf[s_][(h_)*8192 + 0    + w*512]); \
    gl16(bsrc[(h_)*2+1] + (t_)*64, &Bbuf[s_][(h_)*8192 + 4096 + w*512]); }
  #define LDA2(s_, mh_) { _Pragma("unroll") for (int am_ = 0; am_ < 4; ++am_) { \
    af[am_][0] = *(const bf16x8*)((const char*)&Abuf[s_][0] + arow0 + (mh_)*8192 + am_*2048 + ck0); \
    af[am_][1] = *(const bf16x8*)((const char*)&Abuf[s_][0] + arow0 + (mh_)*8192 + am_*2048 + (ck0^64)); } }
  #define LDB2(s_, nh_) { _Pragma("unroll") for (int bn_ = 0; bn_ < 2; ++bn_) { \
    bf[nh_][bn_][0] = *(const bf16x8*)((const char*)&Bbuf[s_][0] + brow0 + (nh_)*4096 + bn_*2048 + ck0); \
    bf[nh_][bn_][1] = *(const bf16x8*)((const char*)&Bbuf[s_][0] + brow0 + (nh_)*4096 + bn_*2048 + (ck0^64)); } }
  #define MM2(mh_, nh_) { __builtin_amdgcn_s_setprio(1); \
    _Pragma("unroll") for (int bn_ = 0; bn_ < 2; ++bn_) \
      _Pragma("unroll") for (int am_ = 0; am_ < 4; ++am_) { \
        acc[(mh_)*4+am_][(nh_)*2+bn_] = __builtin_amdgcn_mfma_f32_16x16x32_bf16(af[am_][0], bf[nh_][bn_][0], acc[(mh_)*4+am_][(nh_)*2+bn_], 0,0,0); \
        acc[(mh_)*4+am_][(nh_)*2+bn_] = __builtin_amdgcn_mfma_f32_16x16x32_bf16(af[am_][1], bf[nh_][bn_][1], acc[(mh_)*4+am_][(nh_)*2+bn_], 0,0,0); } \
    __builtin_amdgcn_s_setprio(0); }

  const int NT2 = 16;
  SA2(0, 0, 0); SA2(0, 1, 0); SB2(0, 0, 0); SB2(0, 1, 0);
  SB2(1, 0, 1); SB2(1, 1, 1);
  WAITV(4);
  BAR();

  #define TILE2(t_, s_, o_) { \
    LDA2(s_, 0); LDB2(s_, 0); LDB2(s_, 1); \
    if ((t_)+1 < NT2) { SA2((t_)+1, 0, o_); SA2((t_)+1, 1, o_); } \
    BAR(); LGKM0(); MM2(0, 0); MM2(0, 1); BAR(); \
    LDA2(s_, 1); \
    if ((t_)+2 < NT2) { SB2((t_)+2, 0, s_); SB2((t_)+2, 1, s_); } \
    BAR(); LGKM0(); MM2(1, 1); MM2(1, 0); \
    if ((t_)+2 < NT2) { WAITV(4); } else { WAITV(0); } \
    BAR(); }

  for (int t = 0; t < NT2; t += 2) {
    TILE2(t, 0, 1);
    TILE2(t + 1, 1, 0);
  }
  #undef TILE2
  #undef SA2
  #undef SB2
  #undef LDA2
  #undef LDB2
  #undef MM2
  #undef SA1
  #undef SB1
  #undef LDA1
  #undef LDB1
  #undef MM1

  unsigned short* dnp = kh ? dn1 : dn0;
  #pragma unroll
  for (int mf = 0; mf < 8; ++mf) {
    const int rloc = wm + (mf >> 2) * 64 + (mf & 3) * 16 + lg * 4;
    #pragma unroll
    for (int nf = 0; nf < 4; ++nf) {
      f32x4 av = acc[mf][nf];
      int col = n0 + wn4 + nf * 16 + lr;
      #pragma unroll
      for (int q = 0; q < 4; ++q) {
        int r = rloc + q;
        if (m0 + r < cntE)
          dnp[(size_t)(rowbase + m0 + r) * HD + col] = f2bf(av[q]);
      }
    }
  }
}

// ---------------- combine ----------------
__global__ __launch_bounds__(256) void k_comb(const unsigned short* __restrict__ dn0,
    const unsigned short* __restrict__ dn1,
    const int* __restrict__ base, const int* __restrict__ slotrec,
    const float* __restrict__ wts, float* __restrict__ out)
{
  const int t = blockIdx.x;
  const int c = threadIdx.x * 4;
  int r0 = slotrec[t * 2], r1 = slotrec[t * 2 + 1];
  int e0 = r0 >> 16, p0 = r0 & 0xffff;
  int e1 = r1 >> 16, p1 = r1 & 0xffff;
  size_t s0 = (size_t)(base[e0] + p0) * HD + c;
  size_t s1 = (size_t)(base[e1] + p1) * HD + c;
  size_t sh = (size_t)(2 * T_TOK + t) * HD + c;
  float w0 = wts[e0 * T_TOK + p0], w1 = wts[e1 * T_TOK + p1];
  u32x2 vs0 = *(const u32x2*)&dn0[sh], vs1 = *(const u32x2*)&dn1[sh];
  u32x2 va0 = *(const u32x2*)&dn0[s0], va1 = *(const u32x2*)&dn1[s0];
  u32x2 vb0 = *(const u32x2*)&dn0[s1], vb1 = *(const u32x2*)&dn1[s1];
  f32x4 o;
  o[0] = (bflo(vs0[0]) + bflo(vs1[0])) + w0 * (bflo(va0[0]) + bflo(va1[0])) + w1 * (bflo(vb0[0]) + bflo(vb1[0]));
  o[1] = (bfhi(vs0[0]) + bfhi(vs1[0])) + w0 * (bfhi(va0[0]) + bfhi(va1[0])) + w1 * (bfhi(vb0[0]) + bfhi(vb1[0]));
  o[2] = (bflo(vs0[1]) + bflo(vs1[1])) + w0 * (bflo(va0[1]) + bflo(va1[1])) + w1 * (bflo(vb0[1]) + bflo(vb1[1]));
  o[3] = (bfhi(vs0[1]) + bfhi(vs1[1])) + w0 * (bfhi(va0[1]) + bfhi(va1[1])) + w1 * (bfhi(vb0[1]) + bfhi(vb1[1]));
  *(f32x4*)&out[(size_t)t * HD + c] = o;
}

extern "C" void kernel_launch(void* const* d_in, const int* in_sizes, int n_in,
                              void* d_out, int out_size, void* d_ws, size_t ws_size,
                              hipStream_t stream)
{
  const float* x    = (const float*)d_in[0];
  const float* gw   = (const float*)d_in[1];
  const float* bias = (const float*)d_in[2];
  const float* Wg   = (const float*)d_in[3];
  const float* Wu   = (const float*)d_in[4];
  const float* Wd   = (const float*)d_in[5];
  const float* Sg   = (const float*)d_in[6];
  const float* Su   = (const float*)d_in[7];
  const float* Sd   = (const float*)d_in[8];
  float* out = (float*)d_out;
  char* ws = (char*)d_ws;

  int*   cnt     = (int*)ws;
  int*   base    = cnt + 16;
  int*   tokens  = (int*)(ws + 512);
  float* wts     = (float*)(ws + 512 + (NE * T_TOK * 4));
  int*   slotrec = (int*)(ws + 512 + 2 * (NE * T_TOK * 4));

  const size_t MB = (size_t)1 << 20;
  unsigned short* xbf = (unsigned short*)(ws + 1 * MB);    // 8 MB
  unsigned short* WdT = (unsigned short*)(ws + 9 * MB);    // 32 MB
  unsigned short* SdT = (unsigned short*)(ws + 41 * MB);   // 4 MB
  unsigned short* Wgu = (unsigned short*)(ws + 45 * MB);   // 64 MB (dead after mlp1)
  unsigned short* Sgu = (unsigned short*)(ws + 109 * MB);  // 8 MB (dead after mlp1)
  unsigned short* actb = (unsigned short*)(ws + 117 * MB); // 48 MB
  unsigned short* dn0 = (unsigned short*)(ws + 45 * MB);   // 24 MB, overlays Wgu
  unsigned short* dn1 = (unsigned short*)(ws + 69 * MB);   // 24 MB, overlays Wgu

  k_zero<<<dim3(1), dim3(64), 0, stream>>>(cnt);
  k_conv<<<dim3(1024 + 2048 + 9216 + 4608), dim3(256), 0, stream>>>(
      x, gw, bias, Wg, Wu, Sg, Su, Wd, Sd,
      xbf, Wgu, Sgu, WdT, SdT, cnt, tokens, wts, slotrec);
  k_fin<<<dim3(1), dim3(64), 0, stream>>>(cnt, base, out);
  k_mlp1<<<dim3(2304), dim3(512), 0, stream>>>(xbf, Wgu, Sgu, cnt, base, tokens, actb);
  k_mlp2<<<dim3(1152), dim3(512), 0, stream>>>(actb, WdT, SdT, cnt, base, dn0, dn1);
  k_comb<<<dim3(T_TOK), dim3(256), 0, stream>>>(dn0, dn1, base, slotrec, wts, out);
}

// Round 14
// 363.332 us; speedup vs baseline: 1.0714x; 1.0135x over previous
//
#include <hip/hip_runtime.h>
#include <hip/hip_bf16.h>

#define T_TOK 4096
#define HD 1024
#define ID 2048
#define NE 8

typedef __attribute__((ext_vector_type(8))) __bf16 bf16x8;
typedef __attribute__((ext_vector_type(4))) float f32x4;
typedef __attribute__((ext_vector_type(4))) unsigned int u32x4;
typedef __attribute__((ext_vector_type(2))) unsigned int u32x2;

#define AS1 __attribute__((address_space(1)))
#define AS3 __attribute__((address_space(3)))

#define WAITV(N) asm volatile("s_waitcnt vmcnt(" #N ")" ::: "memory")
#define BAR()    asm volatile("s_barrier" ::: "memory")
#define LGKM0()  { asm volatile("s_waitcnt lgkmcnt(0)" ::: "memory"); __builtin_amdgcn_sched_barrier(0); }

__device__ __forceinline__ unsigned short f2bf(float f) {
  __hip_bfloat16 h = __float2bfloat16(f);
  return __builtin_bit_cast(unsigned short, h);
}
__device__ __forceinline__ unsigned int pk2(float lo, float hi) {
  return (unsigned int)f2bf(lo) | ((unsigned int)f2bf(hi) << 16);
}
__device__ __forceinline__ float bflo(unsigned int u) { return __builtin_bit_cast(float, u << 16); }
__device__ __forceinline__ float bfhi(unsigned int u) { return __builtin_bit_cast(float, u & 0xffff0000u); }
__device__ __forceinline__ void gl16(const void* g, void* l) {
  __builtin_amdgcn_global_load_lds((const AS1 unsigned int*)g, (AS3 unsigned int*)l, 16, 0, 0);
}

// ---------------- routing ----------------
__global__ void k_zero(int* cnt) { if (threadIdx.x < 32) cnt[threadIdx.x] = 0; }

// route + x fp32->bf16 (x row already in registers)
__device__ __forceinline__ void route_body(int rbid, const float* __restrict__ x,
    const float* __restrict__ gw, const float* __restrict__ bias,
    int* __restrict__ cnt, int* __restrict__ tokens, float* __restrict__ wts,
    int* __restrict__ slotrec, unsigned short* __restrict__ xb)
{
  const int lane = threadIdx.x & 63;
  const int t = rbid * 4 + (threadIdx.x >> 6);
  const float* xr = x + (size_t)t * HD + lane * 16;
  f32x4 xv[4];
  #pragma unroll
  for (int j = 0; j < 4; ++j) xv[j] = *(const f32x4*)(xr + j * 4);
  // xb write (fused x-cvt)
  {
    u32x4 p0 = { pk2(xv[0][0],xv[0][1]), pk2(xv[0][2],xv[0][3]), pk2(xv[1][0],xv[1][1]), pk2(xv[1][2],xv[1][3]) };
    u32x4 p1 = { pk2(xv[2][0],xv[2][1]), pk2(xv[2][2],xv[2][3]), pk2(xv[3][0],xv[3][1]), pk2(xv[3][2],xv[3][3]) };
    unsigned short* xd = xb + (size_t)t * HD + lane * 16;
    *(u32x4*)xd = p0;
    *(u32x4*)(xd + 8) = p1;
  }
  float sc[NE];
  #pragma unroll
  for (int e = 0; e < NE; ++e) {
    const float* gr = gw + e * HD + lane * 16;
    float a = 0.f;
    #pragma unroll
    for (int j = 0; j < 4; ++j) {
      f32x4 gv = *(const f32x4*)(gr + j * 4);
      a += xv[j][0]*gv[0] + xv[j][1]*gv[1] + xv[j][2]*gv[2] + xv[j][3]*gv[3];
    }
    #pragma unroll
    for (int off = 32; off > 0; off >>= 1) a += __shfl_xor(a, off);
    sc[e] = a;
  }
  int i1 = 0; float b1 = sc[0] + bias[0];
  #pragma unroll
  for (int e = 1; e < NE; ++e) { float be = sc[e] + bias[e]; if (be > b1) { b1 = be; i1 = e; } }
  int i2 = -1; float b2 = -3e38f;
  #pragma unroll
  for (int e = 0; e < NE; ++e) { if (e == i1) continue; float be = sc[e] + bias[e]; if (be > b2) { b2 = be; i2 = e; } }
  int a1 = 0; float r1 = sc[0];
  #pragma unroll
  for (int e = 1; e < NE; ++e) if (sc[e] > r1) { r1 = sc[e]; a1 = e; }
  float r2 = -3e38f;
  #pragma unroll
  for (int e = 0; e < NE; ++e) if (e != a1 && sc[e] > r2) r2 = sc[e];
  float w1 = 1.f / (1.f + __expf(-r1));
  float w2 = 1.f / (1.f + __expf(-r2));
  float s = w1 + w2; w1 /= s; w2 /= s;
  if (lane == 0) {
    int p = atomicAdd(&cnt[i1], 1); tokens[i1 * T_TOK + p] = t; wts[i1 * T_TOK + p] = w1;
    slotrec[t * 2] = (i1 << 16) | p;
    p = atomicAdd(&cnt[i2], 1);     tokens[i2 * T_TOK + p] = t; wts[i2 * T_TOK + p] = w2;
    slotrec[t * 2 + 1] = (i2 << 16) | p;
  }
}

__global__ void k_fin(const int* __restrict__ cnt, int* __restrict__ base, float* __restrict__ out)
{
  if (threadIdx.x == 0) {
    int b = 0, mx = 0;
    #pragma unroll
    for (int e = 0; e < NE; ++e) { base[e] = b; b += cnt[e]; if (cnt[e] > mx) mx = cnt[e]; }
    base[NE] = b;
    out[(size_t)T_TOK * HD] = (float)mx * (1.f / 1024.f) - 1.f;  // viol
  }
}

// ---------------- fused route + converts ----------------
// LDS swizzle g(n) = (n ^ (n>>2)) & 7: write-side lanes span 8 bank-groups
// (old n&7 gave only 2 -> 16-way conflict, 12.4M cycles); read-side 8-row
// window still gets 8 distinct g -> conflict-free.
__device__ __forceinline__ void tcvt_tile(const float* __restrict__ src, unsigned short* __restrict__ dst,
                                          int K, int N, int mode, int k0, int n0, unsigned short* tl)
{
  const int t = threadIdx.x;
  const int nc = (t & 15) * 4;
  #pragma unroll
  for (int it = 0; it < 4; ++it) {
    int kr = (t >> 4) + it * 16;
    f32x4 v = *(const f32x4*)&src[(size_t)(k0 + kr) * N + n0 + nc];
    #pragma unroll
    for (int j = 0; j < 4; ++j) {
      int n = nc + j;
      int g = (n ^ (n >> 2)) & 7;
      tl[n * 64 + (((kr >> 3) ^ g) * 8) + (kr & 7)] = f2bf(v[j]);
    }
  }
  __syncthreads();
  #pragma unroll
  for (int it = 0; it < 2; ++it) {
    int idx = t + it * 256;
    int n = idx >> 3, kc8 = idx & 7;
    int g = (n ^ (n >> 2)) & 7;
    u32x4 v = *(const u32x4*)&tl[n * 64 + ((kc8 ^ g) * 8)];
    int nn = n0 + n;
    int vrow = (mode == 0) ? nn : (((nn >> 5) << 6) + (nn & 31) + ((mode == 2) ? 32 : 0));
    *(u32x4*)&dst[(size_t)vrow * K + k0 + kc8 * 8] = v;
  }
}

// blocks 0..1023: route+xcvt; 1024..10239: Wg/Wu/Sg/Su; 10240..14847: Wd/Sd
__global__ __launch_bounds__(256) void k_conv(const float* __restrict__ x,
    const float* __restrict__ gw, const float* __restrict__ bias,
    const float* __restrict__ Wg, const float* __restrict__ Wu,
    const float* __restrict__ Sg, const float* __restrict__ Su,
    const float* __restrict__ Wd, const float* __restrict__ Sd,
    unsigned short* __restrict__ xb, unsigned short* __restrict__ Wgu, unsigned short* __restrict__ Sgu,
    unsigned short* __restrict__ WdT, unsigned short* __restrict__ SdT,
    int* __restrict__ cnt, int* __restrict__ tokens, float* __restrict__ wts, int* __restrict__ slotrec)
{
  __shared__ __attribute__((aligned(16))) unsigned short tl[64 * 64];
  int bid = blockIdx.x;
  if (bid < 1024) {
    route_body(bid, x, gw, bias, cnt, tokens, wts, slotrec, xb);
    return;
  }
  bid -= 1024;
  if (bid < 9216) {
    int z = bid >> 9, rem = bid & 511;
    int bx = rem & 31, by = rem >> 5;
    const float* src; unsigned short* dst; int mode;
    if (z < 8)        { src = Wg + (size_t)z * HD * ID;       dst = Wgu + (size_t)z * 4096 * 1024; mode = 1; }
    else if (z < 16)  { src = Wu + (size_t)(z - 8) * HD * ID; dst = Wgu + (size_t)(z - 8) * 4096 * 1024; mode = 2; }
    else if (z == 16) { src = Sg; dst = Sgu; mode = 1; }
    else              { src = Su; dst = Sgu; mode = 2; }
    tcvt_tile(src, dst, HD, ID, mode, by * 64, bx * 64, tl);
    return;
  }
  bid -= 9216;
  {
    int z = bid >> 9, rem = bid & 511;
    int bx = rem & 15, by = rem >> 4;
    const float* src = (z < 8) ? Wd + (size_t)z * ID * HD : Sd;
    unsigned short* dst = (z < 8) ? WdT + (size_t)z * ID * HD : SdT;
    tcvt_tile(src, dst, ID, HD, 0, by * 64, bx * 64, tl);
  }
}

// bijective chunked XCD mapping over the compacted active-tile list
__device__ __forceinline__ int chunked_vid(int bid, int total) {
  int xcd = bid & 7, idx = bid >> 3;
  int q = total >> 3, r = total & 7;
  int cap = (xcd < r) ? q + 1 : q;
  if (idx >= cap) return -1;
  int base = (xcd < r) ? xcd * (q + 1) : r * (q + 1) + (xcd - r) * q;
  return base + idx;
}

// ================= GEMM1: 256x256 virtual (gate|up interleaved), fat 4-phase =================
__global__ __launch_bounds__(512, 2) void k_mlp1(
    const unsigned short* __restrict__ xb,
    const unsigned short* __restrict__ Wgu, const unsigned short* __restrict__ Sgu,
    const int* __restrict__ cnt, const int* __restrict__ base, const int* __restrict__ tokens,
    unsigned short* __restrict__ act)
{
  __shared__ __attribute__((aligned(16))) unsigned short Abuf[2][16384];
  __shared__ __attribute__((aligned(16))) unsigned short Bbuf[2][16384];

  int total = 0;
  #pragma unroll
  for (int ee = 0; ee < 9; ++ee) {
    int c = (ee == 8) ? T_TOK : cnt[ee];
    total += ((c + 255) >> 8) * 16;
  }
  const int vid = chunked_vid(blockIdx.x, total);
  if (vid < 0) return;
  int e = -1, loc = vid, amv = 1;
  #pragma unroll
  for (int ee = 0; ee < 9; ++ee) {
    int c = (ee == 8) ? T_TOK : cnt[ee];
    int a = (c + 255) >> 8;
    int sz = a * 16;
    if (e < 0) { if (loc < sz) { e = ee; amv = a; } else loc -= sz; }
  }
  int nx = 0; while (loc >= amv) { loc -= amv; ++nx; }
  const int my = loc;

  const int cntE = (e == NE) ? T_TOK : cnt[e];
  const int m0 = my * 256;
  const int n0 = nx * 256;
  const unsigned short* Bsrc = (e == NE) ? Sgu : Wgu + (size_t)e * 4096 * 1024;
  const int rowbase = (e == NE) ? 2 * T_TOK : base[e];
  const int tid = threadIdx.x, lane = tid & 63, w = tid >> 6;
  const int srow = tid >> 3;
  const int kgf = (tid & 7) ^ (srow & 7);

  const unsigned short* asrc[4]; const unsigned short* bsrc[4];
  #pragma unroll
  for (int u = 0; u < 4; ++u) {
    int r = u * 64 + srow;
    int rl = min(m0 + r, cntE - 1);
    int tok = (e == NE) ? rl : tokens[e * T_TOK + rl];
    asrc[u] = xb + (size_t)tok * HD + kgf * 8;
    bsrc[u] = Bsrc + (size_t)(n0 + r) * HD + kgf * 8;
  }

  f32x4 acc[8][4];
  const f32x4 z4 = {0.f, 0.f, 0.f, 0.f};
  #pragma unroll
  for (int i = 0; i < 8; ++i)
    #pragma unroll
    for (int j = 0; j < 4; ++j) acc[i][j] = z4;

  const int lr = lane & 15, lg = lane >> 4;
  const int wm = (w >> 2) * 128;
  const int wn4 = (w & 3) * 64;
  const int ck0 = (lg ^ (lr & 7)) * 16;
  const int arow0 = (wm + lr) * 128;
  const int brow0 = (wn4 + lr) * 128;

  bf16x8 af[4][2], bf[2][2][2];

  #define SA1(t_, h_, s_) { \
    gl16(asrc[(h_)*2+0] + (t_)*64, &Abuf[s_][(h_)*8192 + 0    + w*512]); \
    gl16(asrc[(h_)*2+1] + (t_)*64, &Abuf[s_][(h_)*8192 + 4096 + w*512]); }
  #define SB1(t_, h_, s_) { \
    gl16(bsrc[(h_)*2+0] + (t_)*64, &Bbuf[s_][(h_)*8192 + 0    + w*512]); \
    gl16(bsrc[(h_)*2+1] + (t_)*64, &Bbuf[s_][(h_)*8192 + 4096 + w*512]); }
  #define LDA1(s_, mh_) { _Pragma("unroll") for (int am_ = 0; am_ < 4; ++am_) { \
    af[am_][0] = *(const bf16x8*)((const char*)&Abuf[s_][0] + arow0 + (mh_)*8192 + am_*2048 + ck0); \
    af[am_][1] = *(const bf16x8*)((const char*)&Abuf[s_][0] + arow0 + (mh_)*8192 + am_*2048 + (ck0^64)); } }
  #define LDB1(s_, nh_) { _Pragma("unroll") for (int bn_ = 0; bn_ < 2; ++bn_) { \
    bf[nh_][bn_][0] = *(const bf16x8*)((const char*)&Bbuf[s_][0] + brow0 + (nh_)*4096 + bn_*2048 + ck0); \
    bf[nh_][bn_][1] = *(const bf16x8*)((const char*)&Bbuf[s_][0] + brow0 + (nh_)*4096 + bn_*2048 + (ck0^64)); } }
  #define MM1(mh_, nh_) { __builtin_amdgcn_s_setprio(1); \
    _Pragma("unroll") for (int bn_ = 0; bn_ < 2; ++bn_) \
      _Pragma("unroll") for (int am_ = 0; am_ < 4; ++am_) { \
        acc[(mh_)*4+am_][(nh_)*2+bn_] = __builtin_amdgcn_mfma_f32_16x16x32_bf16(af[am_][0], bf[nh_][bn_][0], acc[(mh_)*4+am_][(nh_)*2+bn_], 0,0,0); \
        acc[(mh_)*4+am_][(nh_)*2+bn_] = __builtin_amdgcn_mfma_f32_16x16x32_bf16(af[am_][1], bf[nh_][bn_][1], acc[(mh_)*4+am_][(nh_)*2+bn_], 0,0,0); } \
    __builtin_amdgcn_s_setprio(0); }

  const int NT1 = 16;
  SA1(0, 0, 0); SA1(0, 1, 0); SB1(0, 0, 0); SB1(0, 1, 0);
  SB1(1, 0, 1); SB1(1, 1, 1);
  WAITV(4);
  BAR();

  #define TILE1(t_, s_, o_) { \
    LDA1(s_, 0); LDB1(s_, 0); LDB1(s_, 1); \
    if ((t_)+1 < NT1) { SA1((t_)+1, 0, o_); SA1((t_)+1, 1, o_); } \
    BAR(); LGKM0(); MM1(0, 0); MM1(0, 1); BAR(); \
    LDA1(s_, 1); \
    if ((t_)+2 < NT1) { SB1((t_)+2, 0, s_); SB1((t_)+2, 1, s_); } \
    BAR(); LGKM0(); MM1(1, 1); MM1(1, 0); \
    if ((t_)+2 < NT1) { WAITV(4); } else { WAITV(0); } \
    BAR(); }

  for (int t = 0; t < NT1; t += 2) {
    TILE1(t, 0, 1);
    TILE1(t + 1, 1, 0);
  }
  #undef TILE1

  const int colbase = ((n0 + wn4) >> 1);
  #pragma unroll
  for (int mf = 0; mf < 8; ++mf) {
    const int rloc = wm + (mf >> 2) * 64 + (mf & 3) * 16 + lg * 4;
    #pragma unroll
    for (int p = 0; p < 2; ++p) {
      f32x4 gv = acc[mf][p], uv = acc[mf][p + 2];
      int col = colbase + p * 16 + lr;
      #pragma unroll
      for (int q = 0; q < 4; ++q) {
        int r = rloc + q;
        if (m0 + r < cntE) {
          float g_ = gv[q], u_ = uv[q];
          act[(size_t)(rowbase + m0 + r) * ID + col] = f2bf((g_ / (1.f + __expf(-g_))) * u_);
        }
      }
    }
  }
}

// ================= GEMM2: 256x256, split-K=2, fat 4-phase =================
__global__ __launch_bounds__(512, 2) void k_mlp2(
    const unsigned short* __restrict__ act,
    const unsigned short* __restrict__ WdT, const unsigned short* __restrict__ SdT,
    const int* __restrict__ cnt, const int* __restrict__ base,
    unsigned short* __restrict__ dn0, unsigned short* __restrict__ dn1)
{
  __shared__ __attribute__((aligned(16))) unsigned short Abuf[2][16384];
  __shared__ __attribute__((aligned(16))) unsigned short Bbuf[2][16384];

  int total = 0;
  #pragma unroll
  for (int ee = 0; ee < 9; ++ee) {
    int c = (ee == 8) ? T_TOK : cnt[ee];
    total += ((c + 255) >> 8) * 8;
  }
  const int vid = chunked_vid(blockIdx.x, total);
  if (vid < 0) return;
  int e = -1, loc = vid, amv = 1;
  #pragma unroll
  for (int ee = 0; ee < 9; ++ee) {
    int c = (ee == 8) ? T_TOK : cnt[ee];
    int a = (c + 255) >> 8;
    int sz = a * 8;
    if (e < 0) { if (loc < sz) { e = ee; amv = a; } else loc -= sz; }
  }
  int nxkh = 0; while (loc >= amv) { loc -= amv; ++nxkh; }
  const int my = loc;
  const int nx = nxkh >> 1, kh = nxkh & 1;

  const int cntE = (e == NE) ? T_TOK : cnt[e];
  const int m0 = my * 256;
  const int n0 = nx * 256;
  const unsigned short* Bsrc = (e == NE) ? SdT : WdT + (size_t)e * ID * HD;
  const int rowbase = (e == NE) ? 2 * T_TOK : base[e];
  const int koff = kh * 1024;
  const int tid = threadIdx.x, lane = tid & 63, w = tid >> 6;
  const int srow = tid >> 3;
  const int kgf = (tid & 7) ^ (srow & 7);

  const unsigned short* asrc[4]; const unsigned short* bsrc[4];
  #pragma unroll
  for (int u = 0; u < 4; ++u) {
    int r = u * 64 + srow;
    int rl = rowbase + min(m0 + r, cntE - 1);
    asrc[u] = act + (size_t)rl * ID + koff + kgf * 8;
    bsrc[u] = Bsrc + (size_t)(n0 + r) * ID + koff + kgf * 8;
  }

  f32x4 acc[8][4];
  const f32x4 z4 = {0.f, 0.f, 0.f, 0.f};
  #pragma unroll
  for (int i = 0; i < 8; ++i)
    #pragma unroll
    for (int j = 0; j < 4; ++j) acc[i][j] = z4;

  const int lr = lane & 15, lg = lane >> 4;
  const int wm = (w >> 2) * 128;
  const int wn4 = (w & 3) * 64;
  const int ck0 = (lg ^ (lr & 7)) * 16;
  const int arow0 = (wm + lr) * 128;
  const int brow0 = (wn4 + lr) * 128;

  bf16x8 af[4][2], bf[2][2][2];

  #define SA2(t_, h_, s_) { \
    gl16(asrc[(h_)*2+0] + (t_)*64, &Abuf[s_][(h_)*8192 + 0    + w*512]); \
    gl16(asrc[(h_)*2+1] + (t_)*64, &Abuf[s_][(h_)*8192 + 4096 + w*512]); }
  #define SB2(t_, h_, s_) { \
    gl16(bsrc[(h_)*2+0] + (t_)*64, &Bbuf[s_][(h_)*8192 + 0    + w*512]); \
    gl16(bsrc[(h_)*2+1] + (t_)*64, &Bbuf[s_][(h_)*8192 + 4096 + w*512]); }
  #define LDA2(s_, mh_) { _Pragma("unroll") for (int am_ = 0; am_ < 4; ++am_) { \
    af[am_][0] = *(const bf16x8*)((const char*)&Abuf[s_][0] + arow0 + (mh_)*8192 + am_*2048 + ck0); \
    af[am_][1] = *(const bf16x8*)((const char*)&Abuf[s_][0] + arow0 + (mh_)*8192 + am_*2048 + (ck0^64)); } }
  #define LDB2(s_, nh_) { _Pragma("unroll") for (int bn_ = 0; bn_ < 2; ++bn_) { \
    bf[nh_][bn_][0] = *(const bf16x8*)((const char*)&Bbuf[s_][0] + brow0 + (nh_)*4096 + bn_*2048 + ck0); \
    bf[nh_][bn_][1] = *(const bf16x8*)((const char*)&Bbuf[s_][0] + brow0 + (nh_)*4096 + bn_*2048 + (ck0^64)); } }
  #define MM2(mh_, nh_) { __builtin_amdgcn_s_setprio(1); \
    _Pragma("unroll") for (int bn_ = 0; bn_ < 2; ++bn_) \
      _Pragma("unroll") for (int am_ = 0; am_ < 4; ++am_) { \
        acc[(mh_)*4+am_][(nh_)*2+bn_] = __builtin_amdgcn_mfma_f32_16x16x32_bf16(af[am_][0], bf[nh_][bn_][0], acc[(mh_)*4+am_][(nh_)*2+bn_], 0,0,0); \
        acc[(mh_)*4+am_][(nh_)*2+bn_] = __builtin_amdgcn_mfma_f32_16x16x32_bf16(af[am_][1], bf[nh_][bn_][1], acc[(mh_)*4+am_][(nh_)*2+bn_], 0,0,0); } \
    __builtin_amdgcn_s_setprio(0); }

  const int NT2 = 16;
  SA2(0, 0, 0); SA2(0, 1, 0); SB2(0, 0, 0); SB2(0, 1, 0);
  SB2(1, 0, 1); SB2(1, 1, 1);
  WAITV(4);
  BAR();

  #define TILE2(t_, s_, o_) { \
    LDA2(s_, 0); LDB2(s_, 0); LDB2(s_, 1); \
    if ((t_)+1 < NT2) { SA2((t_)+1, 0, o_); SA2((t_)+1, 1, o_); } \
    BAR(); LGKM0(); MM2(0, 0); MM2(0, 1); BAR(); \
    LDA2(s_, 1); \
    if ((t_)+2 < NT2) { SB2((t_)+2, 0, s_); SB2((t_)+2, 1, s_); } \
    BAR(); LGKM0(); MM2(1, 1); MM2(1, 0); \
    if ((t_)+2 < NT2) { WAITV(4); } else { WAITV(0); } \
    BAR(); }

  for (int t = 0; t < NT2; t += 2) {
    TILE2(t, 0, 1);
    TILE2(t + 1, 1, 0);
  }
  #undef TILE2
  #undef SA2
  #undef SB2
  #undef LDA2
  #undef LDB2
  #undef MM2
  #undef SA1
  #undef SB1
  #undef LDA1
  #undef LDB1
  #undef MM1

  unsigned short* dnp = kh ? dn1 : dn0;
  #pragma unroll
  for (int mf = 0; mf < 8; ++mf) {
    const int rloc = wm + (mf >> 2) * 64 + (mf & 3) * 16 + lg * 4;
    #pragma unroll
    for (int nf = 0; nf < 4; ++nf) {
      f32x4 av = acc[mf][nf];
      int col = n0 + wn4 + nf * 16 + lr;
      #pragma unroll
      for (int q = 0; q < 4; ++q) {
        int r = rloc + q;
        if (m0 + r < cntE)
          dnp[(size_t)(rowbase + m0 + r) * HD + col] = f2bf(av[q]);
      }
    }
  }
}

// ---------------- combine ----------------
__global__ __launch_bounds__(256) void k_comb(const unsigned short* __restrict__ dn0,
    const unsigned short* __restrict__ dn1,
    const int* __restrict__ base, const int* __restrict__ slotrec,
    const float* __restrict__ wts, float* __restrict__ out)
{
  const int t = blockIdx.x;
  const int c = threadIdx.x * 4;
  int r0 = slotrec[t * 2], r1 = slotrec[t * 2 + 1];
  int e0 = r0 >> 16, p0 = r0 & 0xffff;
  int e1 = r1 >> 16, p1 = r1 & 0xffff;
  size_t s0 = (size_t)(base[e0] + p0) * HD + c;
  size_t s1 = (size_t)(base[e1] + p1) * HD + c;
  size_t sh = (size_t)(2 * T_TOK + t) * HD + c;
  float w0 = wts[e0 * T_TOK + p0], w1 = wts[e1 * T_TOK + p1];
  u32x2 vs0 = *(const u32x2*)&dn0[sh], vs1 = *(const u32x2*)&dn1[sh];
  u32x2 va0 = *(const u32x2*)&dn0[s0], va1 = *(const u32x2*)&dn1[s0];
  u32x2 vb0 = *(const u32x2*)&dn0[s1], vb1 = *(const u32x2*)&dn1[s1];
  f32x4 o;
  o[0] = (bflo(vs0[0]) + bflo(vs1[0])) + w0 * (bflo(va0[0]) + bflo(va1[0])) + w1 * (bflo(vb0[0]) + bflo(vb1[0]));
  o[1] = (bfhi(vs0[0]) + bfhi(vs1[0])) + w0 * (bfhi(va0[0]) + bfhi(va1[0])) + w1 * (bfhi(vb0[0]) + bfhi(vb1[0]));
  o[2] = (bflo(vs0[1]) + bflo(vs1[1])) + w0 * (bflo(va0[1]) + bflo(va1[1])) + w1 * (bflo(vb0[1]) + bflo(vb1[1]));
  o[3] = (bfhi(vs0[1]) + bfhi(vs1[1])) + w0 * (bfhi(va0[1]) + bfhi(va1[1])) + w1 * (bfhi(vb0[1]) + bfhi(vb1[1]));
  *(f32x4*)&out[(size_t)t * HD + c] = o;
}

extern "C" void kernel_launch(void* const* d_in, const int* in_sizes, int n_in,
                              void* d_out, int out_size, void* d_ws, size_t ws_size,
                              hipStream_t stream)
{
  const float* x    = (const float*)d_in[0];
  const float* gw   = (const float*)d_in[1];
  const float* bias = (const float*)d_in[2];
  const float* Wg   = (const float*)d_in[3];
  const float* Wu   = (const float*)d_in[4];
  const float* Wd   = (const float*)d_in[5];
  const float* Sg   = (const float*)d_in[6];
  const float* Su   = (const float*)d_in[7];
  const float* Sd   = (const float*)d_in[8];
  float* out = (float*)d_out;
  char* ws = (char*)d_ws;

  int*   cnt     = (int*)ws;
  int*   base    = cnt + 16;
  int*   tokens  = (int*)(ws + 512);
  float* wts     = (float*)(ws + 512 + (NE * T_TOK * 4));
  int*   slotrec = (int*)(ws + 512 + 2 * (NE * T_TOK * 4));

  const size_t MB = (size_t)1 << 20;
  unsigned short* xbf = (unsigned short*)(ws + 1 * MB);    // 8 MB
  unsigned short* WdT = (unsigned short*)(ws + 9 * MB);    // 32 MB
  unsigned short* SdT = (unsigned short*)(ws + 41 * MB);   // 4 MB
  unsigned short* Wgu = (unsigned short*)(ws + 45 * MB);   // 64 MB (dead after mlp1)
  unsigned short* Sgu = (unsigned short*)(ws + 109 * MB);  // 8 MB (dead after mlp1)
  unsigned short* actb = (unsigned short*)(ws + 117 * MB); // 48 MB
  unsigned short* dn0 = (unsigned short*)(ws + 45 * MB);   // 24 MB, overlays Wgu
  unsigned short* dn1 = (unsigned short*)(ws + 69 * MB);   // 24 MB, overlays Wgu

  k_zero<<<dim3(1), dim3(64), 0, stream>>>(cnt);
  k_conv<<<dim3(1024 + 9216 + 4608), dim3(256), 0, stream>>>(
      x, gw, bias, Wg, Wu, Sg, Su, Wd, Sd,
      xbf, Wgu, Sgu, WdT, SdT, cnt, tokens, wts, slotrec);
  k_fin<<<dim3(1), dim3(64), 0, stream>>>(cnt, base, out);
  k_mlp1<<<dim3(2304), dim3(512), 0, stream>>>(xbf, Wgu, Sgu, cnt, base, tokens, actb);
  k_mlp2<<<dim3(1152), dim3(512), 0, stream>>>(actb, WdT, SdT, cnt, base, dn0, dn1);
  k_comb<<<dim3(T_TOK), dim3(256), 0, stream>>>(dn0, dn1, base, slotrec, wts, out);
}

// Round 15
// 289.220 us; speedup vs baseline: 1.3459x; 1.2563x over previous
//
#include <hip/hip_runtime.h>
#include <hip/hip_bf16.h>

#define T_TOK 4096
#define HD 1024
#define ID 2048
#define NE 8

typedef __attribute__((ext_vector_type(8))) __bf16 bf16x8;
typedef __attribute__((ext_vector_type(4))) float f32x4;
typedef __attribute__((ext_vector_type(4))) unsigned int u32x4;
typedef __attribute__((ext_vector_type(2))) unsigned int u32x2;

#define AS1 __attribute__((address_space(1)))
#define AS3 __attribute__((address_space(3)))

#define WAITV(N) asm volatile("s_waitcnt vmcnt(" #N ")" ::: "memory")
#define BAR()    asm volatile("s_barrier" ::: "memory")
#define LGKM0()  { asm volatile("s_waitcnt lgkmcnt(0)" ::: "memory"); __builtin_amdgcn_sched_barrier(0); }

__device__ __forceinline__ unsigned short f2bf(float f) {
  __hip_bfloat16 h = __float2bfloat16(f);
  return __builtin_bit_cast(unsigned short, h);
}
__device__ __forceinline__ unsigned int pk2(float lo, float hi) {
  return (unsigned int)f2bf(lo) | ((unsigned int)f2bf(hi) << 16);
}
__device__ __forceinline__ float bflo(unsigned int u) { return __builtin_bit_cast(float, u << 16); }
__device__ __forceinline__ float bfhi(unsigned int u) { return __builtin_bit_cast(float, u & 0xffff0000u); }
__device__ __forceinline__ void gl16(const void* g, void* l) {
  __builtin_amdgcn_global_load_lds((const AS1 unsigned int*)g, (AS3 unsigned int*)l, 16, 0, 0);
}

// ---------------- routing ----------------
__global__ void k_zero(int* cnt) { if (threadIdx.x < 32) cnt[threadIdx.x] = 0; }

// fat route block: 4 waves x 4 tokens; LDS-local ranks + 1 global atomic per expert.
__device__ __forceinline__ void route_block(int rbid, const float* __restrict__ x,
    const float* __restrict__ gw, const float* __restrict__ bias,
    int* __restrict__ cnt, int* __restrict__ tokens, float* __restrict__ wts,
    int* __restrict__ slotrec, unsigned short* __restrict__ xb, unsigned short* __restrict__ tl)
{
  int* lcnt  = (int*)tl;          // 8
  int* gbase = lcnt + 8;          // 8
  int* pe    = gbase + 8;         // 32
  int* pr    = pe + 32;           // 32
  int* pt    = pr + 32;           // 32
  float* pw  = (float*)(pt + 32); // 32
  const int tid = threadIdx.x, lane = tid & 63, wv = tid >> 6;
  if (tid < 8) lcnt[tid] = 0;
  __syncthreads();
  #pragma unroll
  for (int i = 0; i < 4; ++i) {
    const int t = rbid * 16 + wv * 4 + i;
    const float* xr = x + (size_t)t * HD + lane * 16;
    f32x4 xv[4];
    #pragma unroll
    for (int j = 0; j < 4; ++j) xv[j] = *(const f32x4*)(xr + j * 4);
    {
      u32x4 p0 = { pk2(xv[0][0],xv[0][1]), pk2(xv[0][2],xv[0][3]), pk2(xv[1][0],xv[1][1]), pk2(xv[1][2],xv[1][3]) };
      u32x4 p1 = { pk2(xv[2][0],xv[2][1]), pk2(xv[2][2],xv[2][3]), pk2(xv[3][0],xv[3][1]), pk2(xv[3][2],xv[3][3]) };
      unsigned short* xd = xb + (size_t)t * HD + lane * 16;
      *(u32x4*)xd = p0;
      *(u32x4*)(xd + 8) = p1;
    }
    float sc[NE];
    #pragma unroll
    for (int e = 0; e < NE; ++e) {
      const float* gr = gw + e * HD + lane * 16;
      float a = 0.f;
      #pragma unroll
      for (int j = 0; j < 4; ++j) {
        f32x4 gv = *(const f32x4*)(gr + j * 4);
        a += xv[j][0]*gv[0] + xv[j][1]*gv[1] + xv[j][2]*gv[2] + xv[j][3]*gv[3];
      }
      #pragma unroll
      for (int off = 32; off > 0; off >>= 1) a += __shfl_xor(a, off);
      sc[e] = a;
    }
    int i1 = 0; float b1 = sc[0] + bias[0];
    #pragma unroll
    for (int e = 1; e < NE; ++e) { float be = sc[e] + bias[e]; if (be > b1) { b1 = be; i1 = e; } }
    int i2 = -1; float b2 = -3e38f;
    #pragma unroll
    for (int e = 0; e < NE; ++e) { if (e == i1) continue; float be = sc[e] + bias[e]; if (be > b2) { b2 = be; i2 = e; } }
    int a1 = 0; float r1 = sc[0];
    #pragma unroll
    for (int e = 1; e < NE; ++e) if (sc[e] > r1) { r1 = sc[e]; a1 = e; }
    float r2 = -3e38f;
    #pragma unroll
    for (int e = 0; e < NE; ++e) if (e != a1 && sc[e] > r2) r2 = sc[e];
    float w1 = 1.f / (1.f + __expf(-r1));
    float w2 = 1.f / (1.f + __expf(-r2));
    float s = w1 + w2; w1 /= s; w2 /= s;
    if (lane == 0) {
      int pk = wv * 8 + i * 2;
      int q1 = atomicAdd(&lcnt[i1], 1);
      pe[pk] = i1; pr[pk] = q1; pt[pk] = t; pw[pk] = w1;
      int q2 = atomicAdd(&lcnt[i2], 1);
      pe[pk+1] = i2; pr[pk+1] = q2; pt[pk+1] = t; pw[pk+1] = w2;
    }
  }
  __syncthreads();
  if (tid < 8) gbase[tid] = atomicAdd(&cnt[tid], lcnt[tid]);
  __syncthreads();
  if (tid < 32) {
    int e = pe[tid], p = gbase[e] + pr[tid];
    tokens[e * T_TOK + p] = pt[tid];
    wts[e * T_TOK + p] = pw[tid];
    slotrec[pt[tid] * 2 + (tid & 1)] = (e << 16) | p;
  }
}

__global__ void k_fin(const int* __restrict__ cnt, int* __restrict__ base, float* __restrict__ out)
{
  if (threadIdx.x == 0) {
    int b = 0, mx = 0;
    #pragma unroll
    for (int e = 0; e < NE; ++e) { base[e] = b; b += cnt[e]; if (cnt[e] > mx) mx = cnt[e]; }
    base[NE] = b;
    out[(size_t)T_TOK * HD] = (float)mx * (1.f / 1024.f) - 1.f;  // viol
  }
}

// ---------------- fused converts + route ----------------
// LDS swizzle g(n) = (n ^ (n>>2)) & 7 (write-side 8-bank spread, read-side conflict-free)
__device__ __forceinline__ void tcvt_tile(const float* __restrict__ src, unsigned short* __restrict__ dst,
                                          int K, int N, int mode, int k0, int n0, unsigned short* tl)
{
  const int t = threadIdx.x;
  const int nc = (t & 15) * 4;
  #pragma unroll
  for (int it = 0; it < 4; ++it) {
    int kr = (t >> 4) + it * 16;
    f32x4 v = *(const f32x4*)&src[(size_t)(k0 + kr) * N + n0 + nc];
    #pragma unroll
    for (int j = 0; j < 4; ++j) {
      int n = nc + j;
      int g = (n ^ (n >> 2)) & 7;
      tl[n * 64 + (((kr >> 3) ^ g) * 8) + (kr & 7)] = f2bf(v[j]);
    }
  }
  __syncthreads();
  #pragma unroll
  for (int it = 0; it < 2; ++it) {
    int idx = t + it * 256;
    int n = idx >> 3, kc8 = idx & 7;
    int g = (n ^ (n >> 2)) & 7;
    u32x4 v = *(const u32x4*)&tl[n * 64 + ((kc8 ^ g) * 8)];
    int nn = n0 + n;
    int vrow = (mode == 0) ? nn : (((nn >> 5) << 6) + (nn & 31) + ((mode == 2) ? 32 : 0));
    *(u32x4*)&dst[(size_t)vrow * K + k0 + kc8 * 8] = v;
  }
}

// blocks 0..9215: Wg/Wu/Sg/Su; 9216..13823: Wd/Sd; 13824..14079: route+xcvt (at tail)
__global__ __launch_bounds__(256) void k_conv(const float* __restrict__ x,
    const float* __restrict__ gw, const float* __restrict__ bias,
    const float* __restrict__ Wg, const float* __restrict__ Wu,
    const float* __restrict__ Sg, const float* __restrict__ Su,
    const float* __restrict__ Wd, const float* __restrict__ Sd,
    unsigned short* __restrict__ xb, unsigned short* __restrict__ Wgu, unsigned short* __restrict__ Sgu,
    unsigned short* __restrict__ WdT, unsigned short* __restrict__ SdT,
    int* __restrict__ cnt, int* __restrict__ tokens, float* __restrict__ wts, int* __restrict__ slotrec)
{
  __shared__ __attribute__((aligned(16))) unsigned short tl[64 * 64];
  int bid = blockIdx.x;
  if (bid < 9216) {
    int z = bid >> 9, rem = bid & 511;
    int bx = rem & 31, by = rem >> 5;
    const float* src; unsigned short* dst; int mode;
    if (z < 8)        { src = Wg + (size_t)z * HD * ID;       dst = Wgu + (size_t)z * 4096 * 1024; mode = 1; }
    else if (z < 16)  { src = Wu + (size_t)(z - 8) * HD * ID; dst = Wgu + (size_t)(z - 8) * 4096 * 1024; mode = 2; }
    else if (z == 16) { src = Sg; dst = Sgu; mode = 1; }
    else              { src = Su; dst = Sgu; mode = 2; }
    tcvt_tile(src, dst, HD, ID, mode, by * 64, bx * 64, tl);
    return;
  }
  bid -= 9216;
  if (bid < 4608) {
    int z = bid >> 9, rem = bid & 511;
    int bx = rem & 15, by = rem >> 4;
    const float* src = (z < 8) ? Wd + (size_t)z * ID * HD : Sd;
    unsigned short* dst = (z < 8) ? WdT + (size_t)z * ID * HD : SdT;
    tcvt_tile(src, dst, ID, HD, 0, by * 64, bx * 64, tl);
    return;
  }
  bid -= 4608;
  route_block(bid, x, gw, bias, cnt, tokens, wts, slotrec, xb, tl);
}

// bijective chunked XCD mapping over the compacted active-tile list
__device__ __forceinline__ int chunked_vid(int bid, int total) {
  int xcd = bid & 7, idx = bid >> 3;
  int q = total >> 3, r = total & 7;
  int cap = (xcd < r) ? q + 1 : q;
  if (idx >= cap) return -1;
  int base = (xcd < r) ? xcd * (q + 1) : r * (q + 1) + (xcd - r) * q;
  return base + idx;
}

// ================= GEMM1: 256x256 virtual (gate|up interleaved), fat 4-phase =================
__global__ __launch_bounds__(512, 2) void k_mlp1(
    const unsigned short* __restrict__ xb,
    const unsigned short* __restrict__ Wgu, const unsigned short* __restrict__ Sgu,
    const int* __restrict__ cnt, const int* __restrict__ base, const int* __restrict__ tokens,
    unsigned short* __restrict__ act)
{
  __shared__ __attribute__((aligned(16))) unsigned short Abuf[2][16384];
  __shared__ __attribute__((aligned(16))) unsigned short Bbuf[2][16384];

  int total = 0;
  #pragma unroll
  for (int ee = 0; ee < 9; ++ee) {
    int c = (ee == 8) ? T_TOK : cnt[ee];
    total += ((c + 255) >> 8) * 16;
  }
  const int vid = chunked_vid(blockIdx.x, total);
  if (vid < 0) return;
  int e = -1, loc = vid, amv = 1;
  #pragma unroll
  for (int ee = 0; ee < 9; ++ee) {
    int c = (ee == 8) ? T_TOK : cnt[ee];
    int a = (c + 255) >> 8;
    int sz = a * 16;
    if (e < 0) { if (loc < sz) { e = ee; amv = a; } else loc -= sz; }
  }
  int nx = 0; while (loc >= amv) { loc -= amv; ++nx; }
  const int my = loc;

  const int cntE = (e == NE) ? T_TOK : cnt[e];
  const int m0 = my * 256;
  const int n0 = nx * 256;
  const unsigned short* Bsrc = (e == NE) ? Sgu : Wgu + (size_t)e * 4096 * 1024;
  const int rowbase = (e == NE) ? 2 * T_TOK : base[e];
  const int tid = threadIdx.x, lane = tid & 63, w = tid >> 6;
  const int srow = tid >> 3;
  const int kgf = (tid & 7) ^ (srow & 7);

  const unsigned short* asrc[4]; const unsigned short* bsrc[4];
  #pragma unroll
  for (int u = 0; u < 4; ++u) {
    int r = u * 64 + srow;
    int rl = min(m0 + r, cntE - 1);
    int tok = (e == NE) ? rl : tokens[e * T_TOK + rl];
    asrc[u] = xb + (size_t)tok * HD + kgf * 8;
    bsrc[u] = Bsrc + (size_t)(n0 + r) * HD + kgf * 8;
  }

  f32x4 acc[8][4];
  const f32x4 z4 = {0.f, 0.f, 0.f, 0.f};
  #pragma unroll
  for (int i = 0; i < 8; ++i)
    #pragma unroll
    for (int j = 0; j < 4; ++j) acc[i][j] = z4;

  const int lr = lane & 15, lg = lane >> 4;
  const int wm = (w >> 2) * 128;
  const int wn4 = (w & 3) * 64;
  const int ck0 = (lg ^ (lr & 7)) * 16;
  const int arow0 = (wm + lr) * 128;
  const int brow0 = (wn4 + lr) * 128;

  bf16x8 af[4][2], bf[2][2][2];

  #define SA1(t_, h_, s_) { \
    gl16(asrc[(h_)*2+0] + (t_)*64, &Abuf[s_][(h_)*8192 + 0    + w*512]); \
    gl16(asrc[(h_)*2+1] + (t_)*64, &Abuf[s_][(h_)*8192 + 4096 + w*512]); }
  #define SB1(t_, h_, s_) { \
    gl16(bsrc[(h_)*2+0] + (t_)*64, &Bbuf[s_][(h_)*8192 + 0    + w*512]); \
    gl16(bsrc[(h_)*2+1] + (t_)*64, &Bbuf[s_][(h_)*8192 + 4096 + w*512]); }
  #define LDA1(s_, mh_) { _Pragma("unroll") for (int am_ = 0; am_ < 4; ++am_) { \
    af[am_][0] = *(const bf16x8*)((const char*)&Abuf[s_][0] + arow0 + (mh_)*8192 + am_*2048 + ck0); \
    af[am_][1] = *(const bf16x8*)((const char*)&Abuf[s_][0] + arow0 + (mh_)*8192 + am_*2048 + (ck0^64)); } }
  #define LDB1(s_, nh_) { _Pragma("unroll") for (int bn_ = 0; bn_ < 2; ++bn_) { \
    bf[nh_][bn_][0] = *(const bf16x8*)((const char*)&Bbuf[s_][0] + brow0 + (nh_)*4096 + bn_*2048 + ck0); \
    bf[nh_][bn_][1] = *(const bf16x8*)((const char*)&Bbuf[s_][0] + brow0 + (nh_)*4096 + bn_*2048 + (ck0^64)); } }
  #define MM1(mh_, nh_) { __builtin_amdgcn_s_setprio(1); \
    _Pragma("unroll") for (int bn_ = 0; bn_ < 2; ++bn_) \
      _Pragma("unroll") for (int am_ = 0; am_ < 4; ++am_) { \
        acc[(mh_)*4+am_][(nh_)*2+bn_] = __builtin_amdgcn_mfma_f32_16x16x32_bf16(af[am_][0], bf[nh_][bn_][0], acc[(mh_)*4+am_][(nh_)*2+bn_], 0,0,0); \
        acc[(mh_)*4+am_][(nh_)*2+bn_] = __builtin_amdgcn_mfma_f32_16x16x32_bf16(af[am_][1], bf[nh_][bn_][1], acc[(mh_)*4+am_][(nh_)*2+bn_], 0,0,0); } \
    __builtin_amdgcn_s_setprio(0); }

  const int NT1 = 16;
  SA1(0, 0, 0); SA1(0, 1, 0); SB1(0, 0, 0); SB1(0, 1, 0);
  SB1(1, 0, 1); SB1(1, 1, 1);
  WAITV(4);
  BAR();

  #define TILE1(t_, s_, o_) { \
    LDA1(s_, 0); LDB1(s_, 0); LDB1(s_, 1); \
    if ((t_)+1 < NT1) { SA1((t_)+1, 0, o_); SA1((t_)+1, 1, o_); } \
    BAR(); LGKM0(); MM1(0, 0); MM1(0, 1); BAR(); \
    LDA1(s_, 1); \
    if ((t_)+2 < NT1) { SB1((t_)+2, 0, s_); SB1((t_)+2, 1, s_); } \
    BAR(); LGKM0(); MM1(1, 1); MM1(1, 0); \
    if ((t_)+2 < NT1) { WAITV(4); } else { WAITV(0); } \
    BAR(); }

  for (int t = 0; t < NT1; t += 2) {
    TILE1(t, 0, 1);
    TILE1(t + 1, 1, 0);
  }
  #undef TILE1

  const int colbase = ((n0 + wn4) >> 1);
  #pragma unroll
  for (int mf = 0; mf < 8; ++mf) {
    const int rloc = wm + (mf >> 2) * 64 + (mf & 3) * 16 + lg * 4;
    #pragma unroll
    for (int p = 0; p < 2; ++p) {
      f32x4 gv = acc[mf][p], uv = acc[mf][p + 2];
      int col = colbase + p * 16 + lr;
      #pragma unroll
      for (int q = 0; q < 4; ++q) {
        int r = rloc + q;
        if (m0 + r < cntE) {
          float g_ = gv[q], u_ = uv[q];
          act[(size_t)(rowbase + m0 + r) * ID + col] = f2bf((g_ / (1.f + __expf(-g_))) * u_);
        }
      }
    }
  }
}

// ================= GEMM2: 256x256, split-K=2, fat 4-phase =================
__global__ __launch_bounds__(512, 2) void k_mlp2(
    const unsigned short* __restrict__ act,
    const unsigned short* __restrict__ WdT, const unsigned short* __restrict__ SdT,
    const int* __restrict__ cnt, const int* __restrict__ base,
    unsigned short* __restrict__ dn0, unsigned short* __restrict__ dn1)
{
  __shared__ __attribute__((aligned(16))) unsigned short Abuf[2][16384];
  __shared__ __attribute__((aligned(16))) unsigned short Bbuf[2][16384];

  int total = 0;
  #pragma unroll
  for (int ee = 0; ee < 9; ++ee) {
    int c = (ee == 8) ? T_TOK : cnt[ee];
    total += ((c + 255) >> 8) * 8;
  }
  const int vid = chunked_vid(blockIdx.x, total);
  if (vid < 0) return;
  int e = -1, loc = vid, amv = 1;
  #pragma unroll
  for (int ee = 0; ee < 9; ++ee) {
    int c = (ee == 8) ? T_TOK : cnt[ee];
    int a = (c + 255) >> 8;
    int sz = a * 8;
    if (e < 0) { if (loc < sz) { e = ee; amv = a; } else loc -= sz; }
  }
  int nxkh = 0; while (loc >= amv) { loc -= amv; ++nxkh; }
  const int my = loc;
  const int nx = nxkh >> 1, kh = nxkh & 1;

  const int cntE = (e == NE) ? T_TOK : cnt[e];
  const int m0 = my * 256;
  const int n0 = nx * 256;
  const unsigned short* Bsrc = (e == NE) ? SdT : WdT + (size_t)e * ID * HD;
  const int rowbase = (e == NE) ? 2 * T_TOK : base[e];
  const int koff = kh * 1024;
  const int tid = threadIdx.x, lane = tid & 63, w = tid >> 6;
  const int srow = tid >> 3;
  const int kgf = (tid & 7) ^ (srow & 7);

  const unsigned short* asrc[4]; const unsigned short* bsrc[4];
  #pragma unroll
  for (int u = 0; u < 4; ++u) {
    int r = u * 64 + srow;
    int rl = rowbase + min(m0 + r, cntE - 1);
    asrc[u] = act + (size_t)rl * ID + koff + kgf * 8;
    bsrc[u] = Bsrc + (size_t)(n0 + r) * ID + koff + kgf * 8;
  }

  f32x4 acc[8][4];
  const f32x4 z4 = {0.f, 0.f, 0.f, 0.f};
  #pragma unroll
  for (int i = 0; i < 8; ++i)
    #pragma unroll
    for (int j = 0; j < 4; ++j) acc[i][j] = z4;

  const int lr = lane & 15, lg = lane >> 4;
  const int wm = (w >> 2) * 128;
  const int wn4 = (w & 3) * 64;
  const int ck0 = (lg ^ (lr & 7)) * 16;
  const int arow0 = (wm + lr) * 128;
  const int brow0 = (wn4 + lr) * 128;

  bf16x8 af[4][2], bf[2][2][2];

  #define SA2(t_, h_, s_) { \
    gl16(asrc[(h_)*2+0] + (t_)*64, &Abuf[s_][(h_)*8192 + 0    + w*512]); \
    gl16(asrc[(h_)*2+1] + (t_)*64, &Abuf[s_][(h_)*8192 + 4096 + w*512]); }
  #define SB2(t_, h_, s_) { \
    gl16(bsrc[(h_)*2+0] + (t_)*64, &Bbuf[s_][(h_)*8192 + 0    + w*512]); \
    gl16(bsrc[(h_)*2+1] + (t_)*64, &Bbuf[s_][(h_)*8192 + 4096 + w*512]); }
  #define LDA2(s_, mh_) { _Pragma("unroll") for (int am_ = 0; am_ < 4; ++am_) { \
    af[am_][0] = *(const bf16x8*)((const char*)&Abuf[s_][0] + arow0 + (mh_)*8192 + am_*2048 + ck0); \
    af[am_][1] = *(const bf16x8*)((const char*)&Abuf[s_][0] + arow0 + (mh_)*8192 + am_*2048 + (ck0^64)); } }
  #define LDB2(s_, nh_) { _Pragma("unroll") for (int bn_ = 0; bn_ < 2; ++bn_) { \
    bf[nh_][bn_][0] = *(const bf16x8*)((const char*)&Bbuf[s_][0] + brow0 + (nh_)*4096 + bn_*2048 + ck0); \
    bf[nh_][bn_][1] = *(const bf16x8*)((const char*)&Bbuf[s_][0] + brow0 + (nh_)*4096 + bn_*2048 + (ck0^64)); } }
  #define MM2(mh_, nh_) { __builtin_amdgcn_s_setprio(1); \
    _Pragma("unroll") for (int bn_ = 0; bn_ < 2; ++bn_) \
      _Pragma("unroll") for (int am_ = 0; am_ < 4; ++am_) { \
        acc[(mh_)*4+am_][(nh_)*2+bn_] = __builtin_amdgcn_mfma_f32_16x16x32_bf16(af[am_][0], bf[nh_][bn_][0], acc[(mh_)*4+am_][(nh_)*2+bn_], 0,0,0); \
        acc[(mh_)*4+am_][(nh_)*2+bn_] = __builtin_amdgcn_mfma_f32_16x16x32_bf16(af[am_][1], bf[nh_][bn_][1], acc[(mh_)*4+am_][(nh_)*2+bn_], 0,0,0); } \
    __builtin_amdgcn_s_setprio(0); }

  const int NT2 = 16;
  SA2(0, 0, 0); SA2(0, 1, 0); SB2(0, 0, 0); SB2(0, 1, 0);
  SB2(1, 0, 1); SB2(1, 1, 1);
  WAITV(4);
  BAR();

  #define TILE2(t_, s_, o_) { \
    LDA2(s_, 0); LDB2(s_, 0); LDB2(s_, 1); \
    if ((t_)+1 < NT2) { SA2((t_)+1, 0, o_); SA2((t_)+1, 1, o_); } \
    BAR(); LGKM0(); MM2(0, 0); MM2(0, 1); BAR(); \
    LDA2(s_, 1); \
    if ((t_)+2 < NT2) { SB2((t_)+2, 0, s_); SB2((t_)+2, 1, s_); } \
    BAR(); LGKM0(); MM2(1, 1); MM2(1, 0); \
    if ((t_)+2 < NT2) { WAITV(4); } else { WAITV(0); } \
    BAR(); }

  for (int t = 0; t < NT2; t += 2) {
    TILE2(t, 0, 1);
    TILE2(t + 1, 1, 0);
  }
  #undef TILE2
  #undef SA2
  #undef SB2
  #undef LDA2
  #undef LDB2
  #undef MM2
  #undef SA1
  #undef SB1
  #undef LDA1
  #undef LDB1
  #undef MM1

  unsigned short* dnp = kh ? dn1 : dn0;
  #pragma unroll
  for (int mf = 0; mf < 8; ++mf) {
    const int rloc = wm + (mf >> 2) * 64 + (mf & 3) * 16 + lg * 4;
    #pragma unroll
    for (int nf = 0; nf < 4; ++nf) {
      f32x4 av = acc[mf][nf];
      int col = n0 + wn4 + nf * 16 + lr;
      #pragma unroll
      for (int q = 0; q < 4; ++q) {
        int r = rloc + q;
        if (m0 + r < cntE)
          dnp[(size_t)(rowbase + m0 + r) * HD + col] = f2bf(av[q]);
      }
    }
  }
}

// ---------------- combine ----------------
__global__ __launch_bounds__(256) void k_comb(const unsigned short* __restrict__ dn0,
    const unsigned short* __restrict__ dn1,
    const int* __restrict__ base, const int* __restrict__ slotrec,
    const float* __restrict__ wts, float* __restrict__ out)
{
  const int t = blockIdx.x;
  const int c = threadIdx.x * 4;
  int r0 = slotrec[t * 2], r1 = slotrec[t * 2 + 1];
  int e0 = r0 >> 16, p0 = r0 & 0xffff;
  int e1 = r1 >> 16, p1 = r1 & 0xffff;
  size_t s0 = (size_t)(base[e0] + p0) * HD + c;
  size_t s1 = (size_t)(base[e1] + p1) * HD + c;
  size_t sh = (size_t)(2 * T_TOK + t) * HD + c;
  float w0 = wts[e0 * T_TOK + p0], w1 = wts[e1 * T_TOK + p1];
  u32x2 vs0 = *(const u32x2*)&dn0[sh], vs1 = *(const u32x2*)&dn1[sh];
  u32x2 va0 = *(const u32x2*)&dn0[s0], va1 = *(const u32x2*)&dn1[s0];
  u32x2 vb0 = *(const u32x2*)&dn0[s1], vb1 = *(const u32x2*)&dn1[s1];
  f32x4 o;
  o[0] = (bflo(vs0[0]) + bflo(vs1[0])) + w0 * (bflo(va0[0]) + bflo(va1[0])) + w1 * (bflo(vb0[0]) + bflo(vb1[0]));
  o[1] = (bfhi(vs0[0]) + bfhi(vs1[0])) + w0 * (bfhi(va0[0]) + bfhi(va1[0])) + w1 * (bfhi(vb0[0]) + bfhi(vb1[0]));
  o[2] = (bflo(vs0[1]) + bflo(vs1[1])) + w0 * (bflo(va0[1]) + bflo(va1[1])) + w1 * (bflo(vb0[1]) + bflo(vb1[1]));
  o[3] = (bfhi(vs0[1]) + bfhi(vs1[1])) + w0 * (bfhi(va0[1]) + bfhi(va1[1])) + w1 * (bfhi(vb0[1]) + bfhi(vb1[1]));
  *(f32x4*)&out[(size_t)t * HD + c] = o;
}

extern "C" void kernel_launch(void* const* d_in, const int* in_sizes, int n_in,
                              void* d_out, int out_size, void* d_ws, size_t ws_size,
                              hipStream_t stream)
{
  const float* x    = (const float*)d_in[0];
  const float* gw   = (const float*)d_in[1];
  const float* bias = (const float*)d_in[2];
  const float* Wg   = (const float*)d_in[3];
  const float* Wu   = (const float*)d_in[4];
  const float* Wd   = (const float*)d_in[5];
  const float* Sg   = (const float*)d_in[6];
  const float* Su   = (const float*)d_in[7];
  const float* Sd   = (const float*)d_in[8];
  float* out = (float*)d_out;
  char* ws = (char*)d_ws;

  int*   cnt     = (int*)ws;
  int*   base    = cnt + 16;
  int*   tokens  = (int*)(ws + 512);
  float* wts     = (float*)(ws + 512 + (NE * T_TOK * 4));
  int*   slotrec = (int*)(ws + 512 + 2 * (NE * T_TOK * 4));

  const size_t MB = (size_t)1 << 20;
  unsigned short* xbf = (unsigned short*)(ws + 1 * MB);    // 8 MB
  unsigned short* WdT = (unsigned short*)(ws + 9 * MB);    // 32 MB
  unsigned short* SdT = (unsigned short*)(ws + 41 * MB);   // 4 MB
  unsigned short* Wgu = (unsigned short*)(ws + 45 * MB);   // 64 MB (dead after mlp1)
  unsigned short* Sgu = (unsigned short*)(ws + 109 * MB);  // 8 MB (dead after mlp1)
  unsigned short* actb = (unsigned short*)(ws + 117 * MB); // 48 MB
  unsigned short* dn0 = (unsigned short*)(ws + 45 * MB);   // 24 MB, overlays Wgu
  unsigned short* dn1 = (unsigned short*)(ws + 69 * MB);   // 24 MB, overlays Wgu

  k_zero<<<dim3(1), dim3(64), 0, stream>>>(cnt);
  k_conv<<<dim3(9216 + 4608 + 256), dim3(256), 0, stream>>>(
      x, gw, bias, Wg, Wu, Sg, Su, Wd, Sd,
      xbf, Wgu, Sgu, WdT, SdT, cnt, tokens, wts, slotrec);
  k_fin<<<dim3(1), dim3(64), 0, stream>>>(cnt, base, out);
  k_mlp1<<<dim3(2304), dim3(512), 0, stream>>>(xbf, Wgu, Sgu, cnt, base, tokens, actb);
  k_mlp2<<<dim3(1152), dim3(512), 0, stream>>>(actb, WdT, SdT, cnt, base, dn0, dn1);
  k_comb<<<dim3(T_TOK), dim3(256), 0, stream>>>(dn0, dn1, base, slotrec, wts, out);
}

// Round 16
// 281.601 us; speedup vs baseline: 1.3823x; 1.0271x over previous
//
#include <hip/hip_runtime.h>
#include <hip/hip_bf16.h>

#define T_TOK 4096
#define HD 1024
#define ID 2048
#define NE 8

typedef __attribute__((ext_vector_type(8))) __bf16 bf16x8;
typedef __attribute__((ext_vector_type(4))) float f32x4;
typedef __attribute__((ext_vector_type(4))) unsigned int u32x4;
typedef __attribute__((ext_vector_type(2))) unsigned int u32x2;

#define AS1 __attribute__((address_space(1)))
#define AS3 __attribute__((address_space(3)))

#define WAITV(N) asm volatile("s_waitcnt vmcnt(" #N ")" ::: "memory")
#define BAR()    asm volatile("s_barrier" ::: "memory")
#define LGKM0()  { asm volatile("s_waitcnt lgkmcnt(0)" ::: "memory"); __builtin_amdgcn_sched_barrier(0); }

__device__ __forceinline__ unsigned short f2bf(float f) {
  __hip_bfloat16 h = __float2bfloat16(f);
  return __builtin_bit_cast(unsigned short, h);
}
__device__ __forceinline__ unsigned int pk2(float lo, float hi) {
  return (unsigned int)f2bf(lo) | ((unsigned int)f2bf(hi) << 16);
}
__device__ __forceinline__ float bflo(unsigned int u) { return __builtin_bit_cast(float, u << 16); }
__device__ __forceinline__ float bfhi(unsigned int u) { return __builtin_bit_cast(float, u & 0xffff0000u); }
__device__ __forceinline__ void gl16(const void* g, void* l) {
  __builtin_amdgcn_global_load_lds((const AS1 unsigned int*)g, (AS3 unsigned int*)l, 16, 0, 0);
}

// ---------------- routing ----------------
__global__ void k_zero(int* cnt) { if (threadIdx.x < 32) cnt[threadIdx.x] = 0; }

// fat route block: 4 waves x 4 tokens; LDS-local ranks + 1 global atomic per expert.
__device__ __forceinline__ void route_block(int rbid, const float* __restrict__ x,
    const float* __restrict__ gw, const float* __restrict__ bias,
    int* __restrict__ cnt, int* __restrict__ tokens, float* __restrict__ wts,
    int* __restrict__ slotrec, unsigned short* __restrict__ xb, unsigned short* __restrict__ tl)
{
  int* lcnt  = (int*)tl;          // 8
  int* gbase = lcnt + 8;          // 8
  int* pe    = gbase + 8;         // 32
  int* pr    = pe + 32;           // 32
  int* pt    = pr + 32;           // 32
  float* pw  = (float*)(pt + 32); // 32
  const int tid = threadIdx.x, lane = tid & 63, wv = tid >> 6;
  if (tid < 8) lcnt[tid] = 0;
  __syncthreads();
  #pragma unroll
  for (int i = 0; i < 4; ++i) {
    const int t = rbid * 16 + wv * 4 + i;
    const float* xr = x + (size_t)t * HD + lane * 16;
    f32x4 xv[4];
    #pragma unroll
    for (int j = 0; j < 4; ++j) xv[j] = *(const f32x4*)(xr + j * 4);
    {
      u32x4 p0 = { pk2(xv[0][0],xv[0][1]), pk2(xv[0][2],xv[0][3]), pk2(xv[1][0],xv[1][1]), pk2(xv[1][2],xv[1][3]) };
      u32x4 p1 = { pk2(xv[2][0],xv[2][1]), pk2(xv[2][2],xv[2][3]), pk2(xv[3][0],xv[3][1]), pk2(xv[3][2],xv[3][3]) };
      unsigned short* xd = xb + (size_t)t * HD + lane * 16;
      *(u32x4*)xd = p0;
      *(u32x4*)(xd + 8) = p1;
    }
    float sc[NE];
    #pragma unroll
    for (int e = 0; e < NE; ++e) {
      const float* gr = gw + e * HD + lane * 16;
      float a = 0.f;
      #pragma unroll
      for (int j = 0; j < 4; ++j) {
        f32x4 gv = *(const f32x4*)(gr + j * 4);
        a += xv[j][0]*gv[0] + xv[j][1]*gv[1] + xv[j][2]*gv[2] + xv[j][3]*gv[3];
      }
      #pragma unroll
      for (int off = 32; off > 0; off >>= 1) a += __shfl_xor(a, off);
      sc[e] = a;
    }
    int i1 = 0; float b1 = sc[0] + bias[0];
    #pragma unroll
    for (int e = 1; e < NE; ++e) { float be = sc[e] + bias[e]; if (be > b1) { b1 = be; i1 = e; } }
    int i2 = -1; float b2 = -3e38f;
    #pragma unroll
    for (int e = 0; e < NE; ++e) { if (e == i1) continue; float be = sc[e] + bias[e]; if (be > b2) { b2 = be; i2 = e; } }
    int a1 = 0; float r1 = sc[0];
    #pragma unroll
    for (int e = 1; e < NE; ++e) if (sc[e] > r1) { r1 = sc[e]; a1 = e; }
    float r2 = -3e38f;
    #pragma unroll
    for (int e = 0; e < NE; ++e) if (e != a1 && sc[e] > r2) r2 = sc[e];
    float w1 = 1.f / (1.f + __expf(-r1));
    float w2 = 1.f / (1.f + __expf(-r2));
    float s = w1 + w2; w1 /= s; w2 /= s;
    if (lane == 0) {
      int pk = wv * 8 + i * 2;
      int q1 = atomicAdd(&lcnt[i1], 1);
      pe[pk] = i1; pr[pk] = q1; pt[pk] = t; pw[pk] = w1;
      int q2 = atomicAdd(&lcnt[i2], 1);
      pe[pk+1] = i2; pr[pk+1] = q2; pt[pk+1] = t; pw[pk+1] = w2;
    }
  }
  __syncthreads();
  if (tid < 8) gbase[tid] = atomicAdd(&cnt[tid], lcnt[tid]);
  __syncthreads();
  if (tid < 32) {
    int e = pe[tid], p = gbase[e] + pr[tid];
    tokens[e * T_TOK + p] = pt[tid];
    wts[e * T_TOK + p] = pw[tid];
    slotrec[pt[tid] * 2 + (tid & 1)] = (e << 16) | p;
  }
}

__global__ void k_fin(const int* __restrict__ cnt, int* __restrict__ base, float* __restrict__ out)
{
  if (threadIdx.x == 0) {
    int b = 0, mx = 0;
    #pragma unroll
    for (int e = 0; e < NE; ++e) { base[e] = b; b += cnt[e]; if (cnt[e] > mx) mx = cnt[e]; }
    base[NE] = b;
    out[(size_t)T_TOK * HD] = (float)mx * (1.f / 1024.f) - 1.f;  // viol
  }
}

// ---------------- converts ----------------
// LDS swizzle g(n) = (n ^ (n>>2)) & 7 (write-side 8-bank spread, read-side conflict-free)
__device__ __forceinline__ void tcvt_tile(const float* __restrict__ src, unsigned short* __restrict__ dst,
                                          int K, int N, int mode, int k0, int n0, unsigned short* tl)
{
  const int t = threadIdx.x;
  const int nc = (t & 15) * 4;
  #pragma unroll
  for (int it = 0; it < 4; ++it) {
    int kr = (t >> 4) + it * 16;
    f32x4 v = *(const f32x4*)&src[(size_t)(k0 + kr) * N + n0 + nc];
    #pragma unroll
    for (int j = 0; j < 4; ++j) {
      int n = nc + j;
      int g = (n ^ (n >> 2)) & 7;
      tl[n * 64 + (((kr >> 3) ^ g) * 8) + (kr & 7)] = f2bf(v[j]);
    }
  }
  __syncthreads();
  #pragma unroll
  for (int it = 0; it < 2; ++it) {
    int idx = t + it * 256;
    int n = idx >> 3, kc8 = idx & 7;
    int g = (n ^ (n >> 2)) & 7;
    u32x4 v = *(const u32x4*)&tl[n * 64 + ((kc8 ^ g) * 8)];
    int nn = n0 + n;
    int vrow = (mode == 0) ? nn : (((nn >> 5) << 6) + (nn & 31) + ((mode == 2) ? 32 : 0));
    *(u32x4*)&dst[(size_t)vrow * K + k0 + kc8 * 8] = v;
  }
}

// 512-thread variant (for tail blocks inside k_mlp1); tl = 8KB scratch
__device__ __forceinline__ void tcvt_tile512(const float* __restrict__ src, unsigned short* __restrict__ dst,
                                             int K, int N, int k0, int n0, unsigned short* tl)
{
  const int t = threadIdx.x;
  const int nc = (t & 15) * 4;
  #pragma unroll
  for (int it = 0; it < 2; ++it) {
    int kr = (t >> 4) + it * 32;
    f32x4 v = *(const f32x4*)&src[(size_t)(k0 + kr) * N + n0 + nc];
    #pragma unroll
    for (int j = 0; j < 4; ++j) {
      int n = nc + j;
      int g = (n ^ (n >> 2)) & 7;
      tl[n * 64 + (((kr >> 3) ^ g) * 8) + (kr & 7)] = f2bf(v[j]);
    }
  }
  __syncthreads();
  {
    int n = t >> 3, kc8 = t & 7;
    int g = (n ^ (n >> 2)) & 7;
    u32x4 v = *(const u32x4*)&tl[n * 64 + ((kc8 ^ g) * 8)];
    *(u32x4*)&dst[(size_t)(n0 + n) * K + k0 + kc8 * 8] = v;
  }
}

// blocks 0..9215: Wg/Wu/Sg/Su -> Wgu/Sgu; 9216..9471: route+xcvt (tail)
__global__ __launch_bounds__(256) void k_conv(const float* __restrict__ x,
    const float* __restrict__ gw, const float* __restrict__ bias,
    const float* __restrict__ Wg, const float* __restrict__ Wu,
    const float* __restrict__ Sg, const float* __restrict__ Su,
    unsigned short* __restrict__ xb, unsigned short* __restrict__ Wgu, unsigned short* __restrict__ Sgu,
    int* __restrict__ cnt, int* __restrict__ tokens, float* __restrict__ wts, int* __restrict__ slotrec)
{
  __shared__ __attribute__((aligned(16))) unsigned short tl[64 * 64];
  int bid = blockIdx.x;
  if (bid < 9216) {
    int z = bid >> 9, rem = bid & 511;
    int bx = rem & 31, by = rem >> 5;
    const float* src; unsigned short* dst; int mode;
    if (z < 8)        { src = Wg + (size_t)z * HD * ID;       dst = Wgu + (size_t)z * 4096 * 1024; mode = 1; }
    else if (z < 16)  { src = Wu + (size_t)(z - 8) * HD * ID; dst = Wgu + (size_t)(z - 8) * 4096 * 1024; mode = 2; }
    else if (z == 16) { src = Sg; dst = Sgu; mode = 1; }
    else              { src = Su; dst = Sgu; mode = 2; }
    tcvt_tile(src, dst, HD, ID, mode, by * 64, bx * 64, tl);
    return;
  }
  bid -= 9216;
  route_block(bid, x, gw, bias, cnt, tokens, wts, slotrec, xb, tl);
}

// bijective chunked XCD mapping over the compacted active-tile list
__device__ __forceinline__ int chunked_vid(int bid, int total) {
  int xcd = bid & 7, idx = bid >> 3;
  int q = total >> 3, r = total & 7;
  int cap = (xcd < r) ? q + 1 : q;
  if (idx >= cap) return -1;
  int base = (xcd < r) ? xcd * (q + 1) : r * (q + 1) + (xcd - r) * q;
  return base + idx;
}

// ================= GEMM1 (bids 0..2303) + WdT/SdT convert (bids 2304..6911) =================
__global__ __launch_bounds__(512, 2) void k_mlp1(
    const unsigned short* __restrict__ xb,
    const unsigned short* __restrict__ Wgu, const unsigned short* __restrict__ Sgu,
    const float* __restrict__ Wd, const float* __restrict__ Sd,
    unsigned short* __restrict__ WdT, unsigned short* __restrict__ SdT,
    const int* __restrict__ cnt, const int* __restrict__ base, const int* __restrict__ tokens,
    unsigned short* __restrict__ act)
{
  __shared__ __attribute__((aligned(16))) unsigned short Abuf[2][16384];
  __shared__ __attribute__((aligned(16))) unsigned short Bbuf[2][16384];

  if (blockIdx.x >= 2304) {
    // tail: Wd/Sd -> WdT/SdT transpose-convert (consumed only by k_mlp2)
    int bid = blockIdx.x - 2304;
    int z = bid >> 9, rem = bid & 511;
    int bx = rem & 15, by = rem >> 4;
    const float* src = (z < 8) ? Wd + (size_t)z * ID * HD : Sd;
    unsigned short* dst = (z < 8) ? WdT + (size_t)z * ID * HD : SdT;
    tcvt_tile512(src, dst, ID, HD, by * 64, bx * 64, &Abuf[0][0]);
    return;
  }

  int total = 0;
  #pragma unroll
  for (int ee = 0; ee < 9; ++ee) {
    int c = (ee == 8) ? T_TOK : cnt[ee];
    total += ((c + 255) >> 8) * 16;
  }
  const int vid = chunked_vid(blockIdx.x, total);
  if (vid < 0) return;
  int e = -1, loc = vid, amv = 1;
  #pragma unroll
  for (int ee = 0; ee < 9; ++ee) {
    int c = (ee == 8) ? T_TOK : cnt[ee];
    int a = (c + 255) >> 8;
    int sz = a * 16;
    if (e < 0) { if (loc < sz) { e = ee; amv = a; } else loc -= sz; }
  }
  int nx = 0; while (loc >= amv) { loc -= amv; ++nx; }
  const int my = loc;

  const int cntE = (e == NE) ? T_TOK : cnt[e];
  const int m0 = my * 256;
  const int n0 = nx * 256;
  const unsigned short* Bsrc = (e == NE) ? Sgu : Wgu + (size_t)e * 4096 * 1024;
  const int rowbase = (e == NE) ? 2 * T_TOK : base[e];
  const int tid = threadIdx.x, lane = tid & 63, w = tid >> 6;
  const int srow = tid >> 3;
  const int kgf = (tid & 7) ^ (srow & 7);

  const unsigned short* asrc[4]; const unsigned short* bsrc[4];
  #pragma unroll
  for (int u = 0; u < 4; ++u) {
    int r = u * 64 + srow;
    int rl = min(m0 + r, cntE - 1);
    int tok = (e == NE) ? rl : tokens[e * T_TOK + rl];
    asrc[u] = xb + (size_t)tok * HD + kgf * 8;
    bsrc[u] = Bsrc + (size_t)(n0 + r) * HD + kgf * 8;
  }

  f32x4 acc[8][4];
  const f32x4 z4 = {0.f, 0.f, 0.f, 0.f};
  #pragma unroll
  for (int i = 0; i < 8; ++i)
    #pragma unroll
    for (int j = 0; j < 4; ++j) acc[i][j] = z4;

  const int lr = lane & 15, lg = lane >> 4;
  const int wm = (w >> 2) * 128;
  const int wn4 = (w & 3) * 64;
  const int ck0 = (lg ^ (lr & 7)) * 16;
  const int arow0 = (wm + lr) * 128;
  const int brow0 = (wn4 + lr) * 128;

  bf16x8 af[4][2], bf[2][2][2];

  #define SA1(t_, h_, s_) { \
    gl16(asrc[(h_)*2+0] + (t_)*64, &Abuf[s_][(h_)*8192 + 0    + w*512]); \
    gl16(asrc[(h_)*2+1] + (t_)*64, &Abuf[s_][(h_)*8192 + 4096 + w*512]); }
  #define SB1(t_, h_, s_) { \
    gl16(bsrc[(h_)*2+0] + (t_)*64, &Bbuf[s_][(h_)*8192 + 0    + w*512]); \
    gl16(bsrc[(h_)*2+1] + (t_)*64, &Bbuf[s_][(h_)*8192 + 4096 + w*512]); }
  #define LDA1(s_, mh_) { _Pragma("unroll") for (int am_ = 0; am_ < 4; ++am_) { \
    af[am_][0] = *(const bf16x8*)((const char*)&Abuf[s_][0] + arow0 + (mh_)*8192 + am_*2048 + ck0); \
    af[am_][1] = *(const bf16x8*)((const char*)&Abuf[s_][0] + arow0 + (mh_)*8192 + am_*2048 + (ck0^64)); } }
  #define LDB1(s_, nh_) { _Pragma("unroll") for (int bn_ = 0; bn_ < 2; ++bn_) { \
    bf[nh_][bn_][0] = *(const bf16x8*)((const char*)&Bbuf[s_][0] + brow0 + (nh_)*4096 + bn_*2048 + ck0); \
    bf[nh_][bn_][1] = *(const bf16x8*)((const char*)&Bbuf[s_][0] + brow0 + (nh_)*4096 + bn_*2048 + (ck0^64)); } }
  #define MM1(mh_, nh_) { __builtin_amdgcn_s_setprio(1); \
    _Pragma("unroll") for (int bn_ = 0; bn_ < 2; ++bn_) \
      _Pragma("unroll") for (int am_ = 0; am_ < 4; ++am_) { \
        acc[(mh_)*4+am_][(nh_)*2+bn_] = __builtin_amdgcn_mfma_f32_16x16x32_bf16(af[am_][0], bf[nh_][bn_][0], acc[(mh_)*4+am_][(nh_)*2+bn_], 0,0,0); \
        acc[(mh_)*4+am_][(nh_)*2+bn_] = __builtin_amdgcn_mfma_f32_16x16x32_bf16(af[am_][1], bf[nh_][bn_][1], acc[(mh_)*4+am_][(nh_)*2+bn_], 0,0,0); } \
    __builtin_amdgcn_s_setprio(0); }

  const int NT1 = 16;
  SA1(0, 0, 0); SA1(0, 1, 0); SB1(0, 0, 0); SB1(0, 1, 0);
  SB1(1, 0, 1); SB1(1, 1, 1);
  WAITV(4);
  BAR();

  #define TILE1(t_, s_, o_) { \
    LDA1(s_, 0); LDB1(s_, 0); LDB1(s_, 1); \
    if ((t_)+1 < NT1) { SA1((t_)+1, 0, o_); SA1((t_)+1, 1, o_); } \
    BAR(); LGKM0(); MM1(0, 0); MM1(0, 1); BAR(); \
    LDA1(s_, 1); \
    if ((t_)+2 < NT1) { SB1((t_)+2, 0, s_); SB1((t_)+2, 1, s_); } \
    BAR(); LGKM0(); MM1(1, 1); MM1(1, 0); \
    if ((t_)+2 < NT1) { WAITV(4); } else { WAITV(0); } \
    BAR(); }

  for (int t = 0; t < NT1; t += 2) {
    TILE1(t, 0, 1);
    TILE1(t + 1, 1, 0);
  }
  #undef TILE1

  const int colbase = ((n0 + wn4) >> 1);
  #pragma unroll
  for (int mf = 0; mf < 8; ++mf) {
    const int rloc = wm + (mf >> 2) * 64 + (mf & 3) * 16 + lg * 4;
    #pragma unroll
    for (int p = 0; p < 2; ++p) {
      f32x4 gv = acc[mf][p], uv = acc[mf][p + 2];
      int col = colbase + p * 16 + lr;
      #pragma unroll
      for (int q = 0; q < 4; ++q) {
        int r = rloc + q;
        if (m0 + r < cntE) {
          float g_ = gv[q], u_ = uv[q];
          act[(size_t)(rowbase + m0 + r) * ID + col] = f2bf((g_ / (1.f + __expf(-g_))) * u_);
        }
      }
    }
  }
}

// ================= GEMM2: 256x256, split-K=2, fat 4-phase =================
__global__ __launch_bounds__(512, 2) void k_mlp2(
    const unsigned short* __restrict__ act,
    const unsigned short* __restrict__ WdT, const unsigned short* __restrict__ SdT,
    const int* __restrict__ cnt, const int* __restrict__ base,
    unsigned short* __restrict__ dn0, unsigned short* __restrict__ dn1)
{
  __shared__ __attribute__((aligned(16))) unsigned short Abuf[2][16384];
  __shared__ __attribute__((aligned(16))) unsigned short Bbuf[2][16384];

  int total = 0;
  #pragma unroll
  for (int ee = 0; ee < 9; ++ee) {
    int c = (ee == 8) ? T_TOK : cnt[ee];
    total += ((c + 255) >> 8) * 8;
  }
  const int vid = chunked_vid(blockIdx.x, total);
  if (vid < 0) return;
  int e = -1, loc = vid, amv = 1;
  #pragma unroll
  for (int ee = 0; ee < 9; ++ee) {
    int c = (ee == 8) ? T_TOK : cnt[ee];
    int a = (c + 255) >> 8;
    int sz = a * 8;
    if (e < 0) { if (loc < sz) { e = ee; amv = a; } else loc -= sz; }
  }
  int nxkh = 0; while (loc >= amv) { loc -= amv; ++nxkh; }
  const int my = loc;
  const int nx = nxkh >> 1, kh = nxkh & 1;

  const int cntE = (e == NE) ? T_TOK : cnt[e];
  const int m0 = my * 256;
  const int n0 = nx * 256;
  const unsigned short* Bsrc = (e == NE) ? SdT : WdT + (size_t)e * ID * HD;
  const int rowbase = (e == NE) ? 2 * T_TOK : base[e];
  const int koff = kh * 1024;
  const int tid = threadIdx.x, lane = tid & 63, w = tid >> 6;
  const int srow = tid >> 3;
  const int kgf = (tid & 7) ^ (srow & 7);

  const unsigned short* asrc[4]; const unsigned short* bsrc[4];
  #pragma unroll
  for (int u = 0; u < 4; ++u) {
    int r = u * 64 + srow;
    int rl = rowbase + min(m0 + r, cntE - 1);
    asrc[u] = act + (size_t)rl * ID + koff + kgf * 8;
    bsrc[u] = Bsrc + (size_t)(n0 + r) * ID + koff + kgf * 8;
  }

  f32x4 acc[8][4];
  const f32x4 z4 = {0.f, 0.f, 0.f, 0.f};
  #pragma unroll
  for (int i = 0; i < 8; ++i)
    #pragma unroll
    for (int j = 0; j < 4; ++j) acc[i][j] = z4;

  const int lr = lane & 15, lg = lane >> 4;
  const int wm = (w >> 2) * 128;
  const int wn4 = (w & 3) * 64;
  const int ck0 = (lg ^ (lr & 7)) * 16;
  const int arow0 = (wm + lr) * 128;
  const int brow0 = (wn4 + lr) * 128;

  bf16x8 af[4][2], bf[2][2][2];

  #define SA2(t_, h_, s_) { \
    gl16(asrc[(h_)*2+0] + (t_)*64, &Abuf[s_][(h_)*8192 + 0    + w*512]); \
    gl16(asrc[(h_)*2+1] + (t_)*64, &Abuf[s_][(h_)*8192 + 4096 + w*512]); }
  #define SB2(t_, h_, s_) { \
    gl16(bsrc[(h_)*2+0] + (t_)*64, &Bbuf[s_][(h_)*8192 + 0    + w*512]); \
    gl16(bsrc[(h_)*2+1] + (t_)*64, &Bbuf[s_][(h_)*8192 + 4096 + w*512]); }
  #define LDA2(s_, mh_) { _Pragma("unroll") for (int am_ = 0; am_ < 4; ++am_) { \
    af[am_][0] = *(const bf16x8*)((const char*)&Abuf[s_][0] + arow0 + (mh_)*8192 + am_*2048 + ck0); \
    af[am_][1] = *(const bf16x8*)((const char*)&Abuf[s_][0] + arow0 + (mh_)*8192 + am_*2048 + (ck0^64)); } }
  #define LDB2(s_, nh_) { _Pragma("unroll") for (int bn_ = 0; bn_ < 2; ++bn_) { \
    bf[nh_][bn_][0] = *(const bf16x8*)((const char*)&Bbuf[s_][0] + brow0 + (nh_)*4096 + bn_*2048 + ck0); \
    bf[nh_][bn_][1] = *(const bf16x8*)((const char*)&Bbuf[s_][0] + brow0 + (nh_)*4096 + bn_*2048 + (ck0^64)); } }
  #define MM2(mh_, nh_) { __builtin_amdgcn_s_setprio(1); \
    _Pragma("unroll") for (int bn_ = 0; bn_ < 2; ++bn_) \
      _Pragma("unroll") for (int am_ = 0; am_ < 4; ++am_) { \
        acc[(mh_)*4+am_][(nh_)*2+bn_] = __builtin_amdgcn_mfma_f32_16x16x32_bf16(af[am_][0], bf[nh_][bn_][0], acc[(mh_)*4+am_][(nh_)*2+bn_], 0,0,0); \
        acc[(mh_)*4+am_][(nh_)*2+bn_] = __builtin_amdgcn_mfma_f32_16x16x32_bf16(af[am_][1], bf[nh_][bn_][1], acc[(mh_)*4+am_][(nh_)*2+bn_], 0,0,0); } \
    __builtin_amdgcn_s_setprio(0); }

  const int NT2 = 16;
  SA2(0, 0, 0); SA2(0, 1, 0); SB2(0, 0, 0); SB2(0, 1, 0);
  SB2(1, 0, 1); SB2(1, 1, 1);
  WAITV(4);
  BAR();

  #define TILE2(t_, s_, o_) { \
    LDA2(s_, 0); LDB2(s_, 0); LDB2(s_, 1); \
    if ((t_)+1 < NT2) { SA2((t_)+1, 0, o_); SA2((t_)+1, 1, o_); } \
    BAR(); LGKM0(); MM2(0, 0); MM2(0, 1); BAR(); \
    LDA2(s_, 1); \
    if ((t_)+2 < NT2) { SB2((t_)+2, 0, s_); SB2((t_)+2, 1, s_); } \
    BAR(); LGKM0(); MM2(1, 1); MM2(1, 0); \
    if ((t_)+2 < NT2) { WAITV(4); } else { WAITV(0); } \
    BAR(); }

  for (int t = 0; t < NT2; t += 2) {
    TILE2(t, 0, 1);
    TILE2(t + 1, 1, 0);
  }
  #undef TILE2
  #undef SA2
  #undef SB2
  #undef LDA2
  #undef LDB2
  #undef MM2
  #undef SA1
  #undef SB1
  #undef LDA1
  #undef LDB1
  #undef MM1

  unsigned short* dnp = kh ? dn1 : dn0;
  #pragma unroll
  for (int mf = 0; mf < 8; ++mf) {
    const int rloc = wm + (mf >> 2) * 64 + (mf & 3) * 16 + lg * 4;
    #pragma unroll
    for (int nf = 0; nf < 4; ++nf) {
      f32x4 av = acc[mf][nf];
      int col = n0 + wn4 + nf * 16 + lr;
      #pragma unroll
      for (int q = 0; q < 4; ++q) {
        int r = rloc + q;
        if (m0 + r < cntE)
          dnp[(size_t)(rowbase + m0 + r) * HD + col] = f2bf(av[q]);
      }
    }
  }
}

// ---------------- combine ----------------
__global__ __launch_bounds__(256) void k_comb(const unsigned short* __restrict__ dn0,
    const unsigned short* __restrict__ dn1,
    const int* __restrict__ base, const int* __restrict__ slotrec,
    const float* __restrict__ wts, float* __restrict__ out)
{
  const int t = blockIdx.x;
  const int c = threadIdx.x * 4;
  int r0 = slotrec[t * 2], r1 = slotrec[t * 2 + 1];
  int e0 = r0 >> 16, p0 = r0 & 0xffff;
  int e1 = r1 >> 16, p1 = r1 & 0xffff;
  size_t s0 = (size_t)(base[e0] + p0) * HD + c;
  size_t s1 = (size_t)(base[e1] + p1) * HD + c;
  size_t sh = (size_t)(2 * T_TOK + t) * HD + c;
  float w0 = wts[e0 * T_TOK + p0], w1 = wts[e1 * T_TOK + p1];
  u32x2 vs0 = *(const u32x2*)&dn0[sh], vs1 = *(const u32x2*)&dn1[sh];
  u32x2 va0 = *(const u32x2*)&dn0[s0], va1 = *(const u32x2*)&dn1[s0];
  u32x2 vb0 = *(const u32x2*)&dn0[s1], vb1 = *(const u32x2*)&dn1[s1];
  f32x4 o;
  o[0] = (bflo(vs0[0]) + bflo(vs1[0])) + w0 * (bflo(va0[0]) + bflo(va1[0])) + w1 * (bflo(vb0[0]) + bflo(vb1[0]));
  o[1] = (bfhi(vs0[0]) + bfhi(vs1[0])) + w0 * (bfhi(va0[0]) + bfhi(va1[0])) + w1 * (bfhi(vb0[0]) + bfhi(vb1[0]));
  o[2] = (bflo(vs0[1]) + bflo(vs1[1])) + w0 * (bflo(va0[1]) + bflo(va1[1])) + w1 * (bflo(vb0[1]) + bflo(vb1[1]));
  o[3] = (bfhi(vs0[1]) + bfhi(vs1[1])) + w0 * (bfhi(va0[1]) + bfhi(va1[1])) + w1 * (bfhi(vb0[1]) + bfhi(vb1[1]));
  *(f32x4*)&out[(size_t)t * HD + c] = o;
}

extern "C" void kernel_launch(void* const* d_in, const int* in_sizes, int n_in,
                              void* d_out, int out_size, void* d_ws, size_t ws_size,
                              hipStream_t stream)
{
  const float* x    = (const float*)d_in[0];
  const float* gw   = (const float*)d_in[1];
  const float* bias = (const float*)d_in[2];
  const float* Wg   = (const float*)d_in[3];
  const float* Wu   = (const float*)d_in[4];
  const float* Wd   = (const float*)d_in[5];
  const float* Sg   = (const float*)d_in[6];
  const float* Su   = (const float*)d_in[7];
  const float* Sd   = (const float*)d_in[8];
  float* out = (float*)d_out;
  char* ws = (char*)d_ws;

  int*   cnt     = (int*)ws;
  int*   base    = cnt + 16;
  int*   tokens  = (int*)(ws + 512);
  float* wts     = (float*)(ws + 512 + (NE * T_TOK * 4));
  int*   slotrec = (int*)(ws + 512 + 2 * (NE * T_TOK * 4));

  const size_t MB = (size_t)1 << 20;
  unsigned short* xbf = (unsigned short*)(ws + 1 * MB);    // 8 MB
  unsigned short* WdT = (unsigned short*)(ws + 9 * MB);    // 32 MB
  unsigned short* SdT = (unsigned short*)(ws + 41 * MB);   // 4 MB
  unsigned short* Wgu = (unsigned short*)(ws + 45 * MB);   // 64 MB (dead after mlp1)
  unsigned short* Sgu = (unsigned short*)(ws + 109 * MB);  // 8 MB (dead after mlp1)
  unsigned short* actb = (unsigned short*)(ws + 117 * MB); // 48 MB
  unsigned short* dn0 = (unsigned short*)(ws + 45 * MB);   // 24 MB, overlays Wgu
  unsigned short* dn1 = (unsigned short*)(ws + 69 * MB);   // 24 MB, overlays Wgu

  k_zero<<<dim3(1), dim3(64), 0, stream>>>(cnt);
  k_conv<<<dim3(9216 + 256), dim3(256), 0, stream>>>(
      x, gw, bias, Wg, Wu, Sg, Su,
      xbf, Wgu, Sgu, cnt, tokens, wts, slotrec);
  k_fin<<<dim3(1), dim3(64), 0, stream>>>(cnt, base, out);
  k_mlp1<<<dim3(2304 + 4608), dim3(512), 0, stream>>>(xbf, Wgu, Sgu, Wd, Sd, WdT, SdT, cnt, base, tokens, actb);
  k_mlp2<<<dim3(1152), dim3(512), 0, stream>>>(actb, WdT, SdT, cnt, base, dn0, dn1);
  k_comb<<<dim3(T_TOK), dim3(256), 0, stream>>>(dn0, dn1, base, slotrec, wts, out);
}

// Round 17
// 278.785 us; speedup vs baseline: 1.3963x; 1.0101x over previous
//
#include <hip/hip_runtime.h>
#include <hip/hip_bf16.h>

#define T_TOK 4096
#define HD 1024
#define ID 2048
#define NE 8

typedef __attribute__((ext_vector_type(8))) __bf16 bf16x8;
typedef __attribute__((ext_vector_type(4))) float f32x4;
typedef __attribute__((ext_vector_type(4))) unsigned int u32x4;
typedef __attribute__((ext_vector_type(2))) unsigned int u32x2;

#define AS1 __attribute__((address_space(1)))
#define AS3 __attribute__((address_space(3)))

#define WAITV(N) asm volatile("s_waitcnt vmcnt(" #N ")" ::: "memory")
#define BAR()    asm volatile("s_barrier" ::: "memory")
#define LGKM0()  { asm volatile("s_waitcnt lgkmcnt(0)" ::: "memory"); __builtin_amdgcn_sched_barrier(0); }

__device__ __forceinline__ unsigned short f2bf(float f) {
  __hip_bfloat16 h = __float2bfloat16(f);
  return __builtin_bit_cast(unsigned short, h);
}
__device__ __forceinline__ unsigned int pk2(float lo, float hi) {
  return (unsigned int)f2bf(lo) | ((unsigned int)f2bf(hi) << 16);
}
__device__ __forceinline__ float bflo(unsigned int u) { return __builtin_bit_cast(float, u << 16); }
__device__ __forceinline__ float bfhi(unsigned int u) { return __builtin_bit_cast(float, u & 0xffff0000u); }
__device__ __forceinline__ void gl16(const void* g, void* l) {
  __builtin_amdgcn_global_load_lds((const AS1 unsigned int*)g, (AS3 unsigned int*)l, 16, 0, 0);
}

// ---------------- routing ----------------
// fat route block: 4 waves x 4 tokens; LDS-local ranks + 1 global atomic per expert.
__device__ __forceinline__ void route_block(int rbid, const float* __restrict__ x,
    const float* __restrict__ gw, const float* __restrict__ bias,
    int* __restrict__ cnt, int* __restrict__ tokens, float* __restrict__ wts,
    int* __restrict__ slotrec, unsigned short* __restrict__ xb, unsigned short* __restrict__ tl)
{
  int* lcnt  = (int*)tl;          // 8
  int* gbase = lcnt + 8;          // 8
  int* pe    = gbase + 8;         // 32
  int* pr    = pe + 32;           // 32
  int* pt    = pr + 32;           // 32
  float* pw  = (float*)(pt + 32); // 32
  const int tid = threadIdx.x, lane = tid & 63, wv = tid >> 6;
  if (tid < 8) lcnt[tid] = 0;
  __syncthreads();
  #pragma unroll
  for (int i = 0; i < 4; ++i) {
    const int t = rbid * 16 + wv * 4 + i;
    const float* xr = x + (size_t)t * HD + lane * 16;
    f32x4 xv[4];
    #pragma unroll
    for (int j = 0; j < 4; ++j) xv[j] = *(const f32x4*)(xr + j * 4);
    {
      u32x4 p0 = { pk2(xv[0][0],xv[0][1]), pk2(xv[0][2],xv[0][3]), pk2(xv[1][0],xv[1][1]), pk2(xv[1][2],xv[1][3]) };
      u32x4 p1 = { pk2(xv[2][0],xv[2][1]), pk2(xv[2][2],xv[2][3]), pk2(xv[3][0],xv[3][1]), pk2(xv[3][2],xv[3][3]) };
      unsigned short* xd = xb + (size_t)t * HD + lane * 16;
      *(u32x4*)xd = p0;
      *(u32x4*)(xd + 8) = p1;
    }
    float sc[NE];
    #pragma unroll
    for (int e = 0; e < NE; ++e) {
      const float* gr = gw + e * HD + lane * 16;
      float a = 0.f;
      #pragma unroll
      for (int j = 0; j < 4; ++j) {
        f32x4 gv = *(const f32x4*)(gr + j * 4);
        a += xv[j][0]*gv[0] + xv[j][1]*gv[1] + xv[j][2]*gv[2] + xv[j][3]*gv[3];
      }
      #pragma unroll
      for (int off = 32; off > 0; off >>= 1) a += __shfl_xor(a, off);
      sc[e] = a;
    }
    int i1 = 0; float b1 = sc[0] + bias[0];
    #pragma unroll
    for (int e = 1; e < NE; ++e) { float be = sc[e] + bias[e]; if (be > b1) { b1 = be; i1 = e; } }
    int i2 = -1; float b2 = -3e38f;
    #pragma unroll
    for (int e = 0; e < NE; ++e) { if (e == i1) continue; float be = sc[e] + bias[e]; if (be > b2) { b2 = be; i2 = e; } }
    int a1 = 0; float r1 = sc[0];
    #pragma unroll
    for (int e = 1; e < NE; ++e) if (sc[e] > r1) { r1 = sc[e]; a1 = e; }
    float r2 = -3e38f;
    #pragma unroll
    for (int e = 0; e < NE; ++e) if (e != a1 && sc[e] > r2) r2 = sc[e];
    float w1 = 1.f / (1.f + __expf(-r1));
    float w2 = 1.f / (1.f + __expf(-r2));
    float s = w1 + w2; w1 /= s; w2 /= s;
    if (lane == 0) {
      int pk = wv * 8 + i * 2;
      int q1 = atomicAdd(&lcnt[i1], 1);
      pe[pk] = i1; pr[pk] = q1; pt[pk] = t; pw[pk] = w1;
      int q2 = atomicAdd(&lcnt[i2], 1);
      pe[pk+1] = i2; pr[pk+1] = q2; pt[pk+1] = t; pw[pk+1] = w2;
    }
  }
  __syncthreads();
  if (tid < 8) gbase[tid] = atomicAdd(&cnt[tid], lcnt[tid]);
  __syncthreads();
  if (tid < 32) {
    int e = pe[tid], p = gbase[e] + pr[tid];
    tokens[e * T_TOK + p] = pt[tid];
    wts[e * T_TOK + p] = pw[tid];
    slotrec[pt[tid] * 2 + (tid & 1)] = (e << 16) | p;
  }
}

// ---------------- converts ----------------
// LDS swizzle g(n) = (n ^ (n>>2)) & 7 (write-side 8-bank spread, read-side conflict-free)
__device__ __forceinline__ void tcvt_tile(const float* __restrict__ src, unsigned short* __restrict__ dst,
                                          int K, int N, int mode, int k0, int n0, unsigned short* tl)
{
  const int t = threadIdx.x;
  const int nc = (t & 15) * 4;
  #pragma unroll
  for (int it = 0; it < 4; ++it) {
    int kr = (t >> 4) + it * 16;
    f32x4 v = *(const f32x4*)&src[(size_t)(k0 + kr) * N + n0 + nc];
    #pragma unroll
    for (int j = 0; j < 4; ++j) {
      int n = nc + j;
      int g = (n ^ (n >> 2)) & 7;
      tl[n * 64 + (((kr >> 3) ^ g) * 8) + (kr & 7)] = f2bf(v[j]);
    }
  }
  __syncthreads();
  #pragma unroll
  for (int it = 0; it < 2; ++it) {
    int idx = t + it * 256;
    int n = idx >> 3, kc8 = idx & 7;
    int g = (n ^ (n >> 2)) & 7;
    u32x4 v = *(const u32x4*)&tl[n * 64 + ((kc8 ^ g) * 8)];
    int nn = n0 + n;
    int vrow = (mode == 0) ? nn : (((nn >> 5) << 6) + (nn & 31) + ((mode == 2) ? 32 : 0));
    *(u32x4*)&dst[(size_t)vrow * K + k0 + kc8 * 8] = v;
  }
}

// 512-thread variant (tail blocks inside k_mlp1); tl = 8KB scratch
__device__ __forceinline__ void tcvt_tile512(const float* __restrict__ src, unsigned short* __restrict__ dst,
                                             int K, int N, int k0, int n0, unsigned short* tl)
{
  const int t = threadIdx.x;
  const int nc = (t & 15) * 4;
  #pragma unroll
  for (int it = 0; it < 2; ++it) {
    int kr = (t >> 4) + it * 32;
    f32x4 v = *(const f32x4*)&src[(size_t)(k0 + kr) * N + n0 + nc];
    #pragma unroll
    for (int j = 0; j < 4; ++j) {
      int n = nc + j;
      int g = (n ^ (n >> 2)) & 7;
      tl[n * 64 + (((kr >> 3) ^ g) * 8) + (kr & 7)] = f2bf(v[j]);
    }
  }
  __syncthreads();
  {
    int n = t >> 3, kc8 = t & 7;
    int g = (n ^ (n >> 2)) & 7;
    u32x4 v = *(const u32x4*)&tl[n * 64 + ((kc8 ^ g) * 8)];
    *(u32x4*)&dst[(size_t)(n0 + n) * K + k0 + kc8 * 8] = v;
  }
}

// blocks 0..9215: Wg/Wu/Sg/Su -> Wgu/Sgu; 9216..9471: route+xcvt (tail)
__global__ __launch_bounds__(256) void k_conv(const float* __restrict__ x,
    const float* __restrict__ gw, const float* __restrict__ bias,
    const float* __restrict__ Wg, const float* __restrict__ Wu,
    const float* __restrict__ Sg, const float* __restrict__ Su,
    unsigned short* __restrict__ xb, unsigned short* __restrict__ Wgu, unsigned short* __restrict__ Sgu,
    int* __restrict__ cnt, int* __restrict__ tokens, float* __restrict__ wts, int* __restrict__ slotrec)
{
  __shared__ __attribute__((aligned(16))) unsigned short tl[64 * 64];
  int bid = blockIdx.x;
  if (bid < 9216) {
    int z = bid >> 9, rem = bid & 511;
    int bx = rem & 31, by = rem >> 5;
    const float* src; unsigned short* dst; int mode;
    if (z < 8)        { src = Wg + (size_t)z * HD * ID;       dst = Wgu + (size_t)z * 4096 * 1024; mode = 1; }
    else if (z < 16)  { src = Wu + (size_t)(z - 8) * HD * ID; dst = Wgu + (size_t)(z - 8) * 4096 * 1024; mode = 2; }
    else if (z == 16) { src = Sg; dst = Sgu; mode = 1; }
    else              { src = Su; dst = Sgu; mode = 2; }
    tcvt_tile(src, dst, HD, ID, mode, by * 64, bx * 64, tl);
    return;
  }
  bid -= 9216;
  route_block(bid, x, gw, bias, cnt, tokens, wts, slotrec, xb, tl);
}

// bijective chunked XCD mapping over the compacted active-tile list
__device__ __forceinline__ int chunked_vid(int bid, int total) {
  int xcd = bid & 7, idx = bid >> 3;
  int q = total >> 3, r = total & 7;
  int cap = (xcd < r) ? q + 1 : q;
  if (idx >= cap) return -1;
  int base = (xcd < r) ? xcd * (q + 1) : r * (q + 1) + (xcd - r) * q;
  return base + idx;
}

// ================= GEMM1 (bids 0..2303) + WdT/SdT convert (bids 2304..6911) =================
__global__ __launch_bounds__(512, 2) void k_mlp1(
    const unsigned short* __restrict__ xb,
    const unsigned short* __restrict__ Wgu, const unsigned short* __restrict__ Sgu,
    const float* __restrict__ Wd, const float* __restrict__ Sd,
    unsigned short* __restrict__ WdT, unsigned short* __restrict__ SdT,
    const int* __restrict__ cnt, const int* __restrict__ tokens,
    unsigned short* __restrict__ act)
{
  __shared__ __attribute__((aligned(16))) unsigned short Abuf[2][16384];
  __shared__ __attribute__((aligned(16))) unsigned short Bbuf[2][16384];

  if (blockIdx.x >= 2304) {
    int bid = blockIdx.x - 2304;
    int z = bid >> 9, rem = bid & 511;
    int bx = rem & 15, by = rem >> 4;
    const float* src = (z < 8) ? Wd + (size_t)z * ID * HD : Sd;
    unsigned short* dst = (z < 8) ? WdT + (size_t)z * ID * HD : SdT;
    tcvt_tile512(src, dst, ID, HD, by * 64, bx * 64, &Abuf[0][0]);
    return;
  }

  int total = 0;
  #pragma unroll
  for (int ee = 0; ee < 9; ++ee) {
    int c = (ee == 8) ? T_TOK : cnt[ee];
    total += ((c + 255) >> 8) * 16;
  }
  const int vid = chunked_vid(blockIdx.x, total);
  if (vid < 0) return;
  int e = -1, loc = vid, amv = 1, rb = 0;
  #pragma unroll
  for (int ee = 0; ee < 9; ++ee) {
    int c = (ee == 8) ? T_TOK : cnt[ee];
    int a = (c + 255) >> 8;
    int sz = a * 16;
    if (e < 0) { if (loc < sz) { e = ee; amv = a; } else { loc -= sz; rb += c; } }
  }
  int nx = 0; while (loc >= amv) { loc -= amv; ++nx; }
  const int my = loc;

  const int cntE = (e == NE) ? T_TOK : cnt[e];
  const int m0 = my * 256;
  const int n0 = nx * 256;
  const unsigned short* Bsrc = (e == NE) ? Sgu : Wgu + (size_t)e * 4096 * 1024;
  const int rowbase = (e == NE) ? 2 * T_TOK : rb;
  const int tid = threadIdx.x, lane = tid & 63, w = tid >> 6;
  const int srow = tid >> 3;
  const int kgf = (tid & 7) ^ (srow & 7);

  const unsigned short* asrc[4]; const unsigned short* bsrc[4];
  #pragma unroll
  for (int u = 0; u < 4; ++u) {
    int r = u * 64 + srow;
    int rl = min(m0 + r, cntE - 1);
    int tok = (e == NE) ? rl : tokens[e * T_TOK + rl];
    asrc[u] = xb + (size_t)tok * HD + kgf * 8;
    bsrc[u] = Bsrc + (size_t)(n0 + r) * HD + kgf * 8;
  }

  f32x4 acc[8][4];
  const f32x4 z4 = {0.f, 0.f, 0.f, 0.f};
  #pragma unroll
  for (int i = 0; i < 8; ++i)
    #pragma unroll
    for (int j = 0; j < 4; ++j) acc[i][j] = z4;

  const int lr = lane & 15, lg = lane >> 4;
  const int wm = (w >> 2) * 128;
  const int wn4 = (w & 3) * 64;
  const int ck0 = (lg ^ (lr & 7)) * 16;
  const int arow0 = (wm + lr) * 128;
  const int brow0 = (wn4 + lr) * 128;

  bf16x8 af[4][2], bf[2][2][2];

  #define SA1(t_, h_, s_) { \
    gl16(asrc[(h_)*2+0] + (t_)*64, &Abuf[s_][(h_)*8192 + 0    + w*512]); \
    gl16(asrc[(h_)*2+1] + (t_)*64, &Abuf[s_][(h_)*8192 + 4096 + w*512]); }
  #define SB1(t_, h_, s_) { \
    gl16(bsrc[(h_)*2+0] + (t_)*64, &Bbuf[s_][(h_)*8192 + 0    + w*512]); \
    gl16(bsrc[(h_)*2+1] + (t_)*64, &Bbuf[s_][(h_)*8192 + 4096 + w*512]); }
  #define LDA1(s_, mh_) { _Pragma("unroll") for (int am_ = 0; am_ < 4; ++am_) { \
    af[am_][0] = *(const bf16x8*)((const char*)&Abuf[s_][0] + arow0 + (mh_)*8192 + am_*2048 + ck0); \
    af[am_][1] = *(const bf16x8*)((const char*)&Abuf[s_][0] + arow0 + (mh_)*8192 + am_*2048 + (ck0^64)); } }
  #define LDB1(s_, nh_) { _Pragma("unroll") for (int bn_ = 0; bn_ < 2; ++bn_) { \
    bf[nh_][bn_][0] = *(const bf16x8*)((const char*)&Bbuf[s_][0] + brow0 + (nh_)*4096 + bn_*2048 + ck0); \
    bf[nh_][bn_][1] = *(const bf16x8*)((const char*)&Bbuf[s_][0] + brow0 + (nh_)*4096 + bn_*2048 + (ck0^64)); } }
  #define MM1(mh_, nh_) { __builtin_amdgcn_s_setprio(1); \
    _Pragma("unroll") for (int bn_ = 0; bn_ < 2; ++bn_) \
      _Pragma("unroll") for (int am_ = 0; am_ < 4; ++am_) { \
        acc[(mh_)*4+am_][(nh_)*2+bn_] = __builtin_amdgcn_mfma_f32_16x16x32_bf16(af[am_][0], bf[nh_][bn_][0], acc[(mh_)*4+am_][(nh_)*2+bn_], 0,0,0); \
        acc[(mh_)*4+am_][(nh_)*2+bn_] = __builtin_amdgcn_mfma_f32_16x16x32_bf16(af[am_][1], bf[nh_][bn_][1], acc[(mh_)*4+am_][(nh_)*2+bn_], 0,0,0); } \
    __builtin_amdgcn_s_setprio(0); }

  const int NT1 = 16;
  SA1(0, 0, 0); SA1(0, 1, 0); SB1(0, 0, 0); SB1(0, 1, 0);
  SB1(1, 0, 1); SB1(1, 1, 1);
  WAITV(4);
  BAR();

  #define TILE1(t_, s_, o_) { \
    LDA1(s_, 0); LDB1(s_, 0); LDB1(s_, 1); \
    if ((t_)+1 < NT1) { SA1((t_)+1, 0, o_); SA1((t_)+1, 1, o_); } \
    BAR(); LGKM0(); MM1(0, 0); MM1(0, 1); BAR(); \
    LDA1(s_, 1); \
    if ((t_)+2 < NT1) { SB1((t_)+2, 0, s_); SB1((t_)+2, 1, s_); } \
    BAR(); LGKM0(); MM1(1, 1); MM1(1, 0); \
    if ((t_)+2 < NT1) { WAITV(4); } else { WAITV(0); } \
    BAR(); }

  for (int t = 0; t < NT1; t += 2) {
    TILE1(t, 0, 1);
    TILE1(t + 1, 1, 0);
  }
  #undef TILE1

  const int colbase = ((n0 + wn4) >> 1);
  #pragma unroll
  for (int mf = 0; mf < 8; ++mf) {
    const int rloc = wm + (mf >> 2) * 64 + (mf & 3) * 16 + lg * 4;
    #pragma unroll
    for (int p = 0; p < 2; ++p) {
      f32x4 gv = acc[mf][p], uv = acc[mf][p + 2];
      int col = colbase + p * 16 + lr;
      #pragma unroll
      for (int q = 0; q < 4; ++q) {
        int r = rloc + q;
        if (m0 + r < cntE) {
          float g_ = gv[q], u_ = uv[q];
          act[(size_t)(rowbase + m0 + r) * ID + col] = f2bf((g_ / (1.f + __expf(-g_))) * u_);
        }
      }
    }
  }
}

// ================= GEMM2: 256x256, split-K=2, fat 4-phase =================
__global__ __launch_bounds__(512, 2) void k_mlp2(
    const unsigned short* __restrict__ act,
    const unsigned short* __restrict__ WdT, const unsigned short* __restrict__ SdT,
    const int* __restrict__ cnt,
    unsigned short* __restrict__ dn0, unsigned short* __restrict__ dn1)
{
  __shared__ __attribute__((aligned(16))) unsigned short Abuf[2][16384];
  __shared__ __attribute__((aligned(16))) unsigned short Bbuf[2][16384];

  int total = 0;
  #pragma unroll
  for (int ee = 0; ee < 9; ++ee) {
    int c = (ee == 8) ? T_TOK : cnt[ee];
    total += ((c + 255) >> 8) * 8;
  }
  const int vid = chunked_vid(blockIdx.x, total);
  if (vid < 0) return;
  int e = -1, loc = vid, amv = 1, rb = 0;
  #pragma unroll
  for (int ee = 0; ee < 9; ++ee) {
    int c = (ee == 8) ? T_TOK : cnt[ee];
    int a = (c + 255) >> 8;
    int sz = a * 8;
    if (e < 0) { if (loc < sz) { e = ee; amv = a; } else { loc -= sz; rb += c; } }
  }
  int nxkh = 0; while (loc >= amv) { loc -= amv; ++nxkh; }
  const int my = loc;
  const int nx = nxkh >> 1, kh = nxkh & 1;

  const int cntE = (e == NE) ? T_TOK : cnt[e];
  const int m0 = my * 256;
  const int n0 = nx * 256;
  const unsigned short* Bsrc = (e == NE) ? SdT : WdT + (size_t)e * ID * HD;
  const int rowbase = (e == NE) ? 2 * T_TOK : rb;
  const int koff = kh * 1024;
  const int tid = threadIdx.x, lane = tid & 63, w = tid >> 6;
  const int srow = tid >> 3;
  const int kgf = (tid & 7) ^ (srow & 7);

  const unsigned short* asrc[4]; const unsigned short* bsrc[4];
  #pragma unroll
  for (int u = 0; u < 4; ++u) {
    int r = u * 64 + srow;
    int rl = rowbase + min(m0 + r, cntE - 1);
    asrc[u] = act + (size_t)rl * ID + koff + kgf * 8;
    bsrc[u] = Bsrc + (size_t)(n0 + r) * ID + koff + kgf * 8;
  }

  f32x4 acc[8][4];
  const f32x4 z4 = {0.f, 0.f, 0.f, 0.f};
  #pragma unroll
  for (int i = 0; i < 8; ++i)
    #pragma unroll
    for (int j = 0; j < 4; ++j) acc[i][j] = z4;

  const int lr = lane & 15, lg = lane >> 4;
  const int wm = (w >> 2) * 128;
  const int wn4 = (w & 3) * 64;
  const int ck0 = (lg ^ (lr & 7)) * 16;
  const int arow0 = (wm + lr) * 128;
  const int brow0 = (wn4 + lr) * 128;

  bf16x8 af[4][2], bf[2][2][2];

  #define SA2(t_, h_, s_) { \
    gl16(asrc[(h_)*2+0] + (t_)*64, &Abuf[s_][(h_)*8192 + 0    + w*512]); \
    gl16(asrc[(h_)*2+1] + (t_)*64, &Abuf[s_][(h_)*8192 + 4096 + w*512]); }
  #define SB2(t_, h_, s_) { \
    gl16(bsrc[(h_)*2+0] + (t_)*64, &Bbuf[s_][(h_)*8192 + 0    + w*512]); \
    gl16(bsrc[(h_)*2+1] + (t_)*64, &Bbuf[s_][(h_)*8192 + 4096 + w*512]); }
  #define LDA2(s_, mh_) { _Pragma("unroll") for (int am_ = 0; am_ < 4; ++am_) { \
    af[am_][0] = *(const bf16x8*)((const char*)&Abuf[s_][0] + arow0 + (mh_)*8192 + am_*2048 + ck0); \
    af[am_][1] = *(const bf16x8*)((const char*)&Abuf[s_][0] + arow0 + (mh_)*8192 + am_*2048 + (ck0^64)); } }
  #define LDB2(s_, nh_) { _Pragma("unroll") for (int bn_ = 0; bn_ < 2; ++bn_) { \
    bf[nh_][bn_][0] = *(const bf16x8*)((const char*)&Bbuf[s_][0] + brow0 + (nh_)*4096 + bn_*2048 + ck0); \
    bf[nh_][bn_][1] = *(const bf16x8*)((const char*)&Bbuf[s_][0] + brow0 + (nh_)*4096 + bn_*2048 + (ck0^64)); } }
  #define MM2(mh_, nh_) { __builtin_amdgcn_s_setprio(1); \
    _Pragma("unroll") for (int bn_ = 0; bn_ < 2; ++bn_) \
      _Pragma("unroll") for (int am_ = 0; am_ < 4; ++am_) { \
        acc[(mh_)*4+am_][(nh_)*2+bn_] = __builtin_amdgcn_mfma_f32_16x16x32_bf16(af[am_][0], bf[nh_][bn_][0], acc[(mh_)*4+am_][(nh_)*2+bn_], 0,0,0); \
        acc[(mh_)*4+am_][(nh_)*2+bn_] = __builtin_amdgcn_mfma_f32_16x16x32_bf16(af[am_][1], bf[nh_][bn_][1], acc[(mh_)*4+am_][(nh_)*2+bn_], 0,0,0); } \
    __builtin_amdgcn_s_setprio(0); }

  const int NT2 = 16;
  SA2(0, 0, 0); SA2(0, 1, 0); SB2(0, 0, 0); SB2(0, 1, 0);
  SB2(1, 0, 1); SB2(1, 1, 1);
  WAITV(4);
  BAR();

  #define TILE2(t_, s_, o_) { \
    LDA2(s_, 0); LDB2(s_, 0); LDB2(s_, 1); \
    if ((t_)+1 < NT2) { SA2((t_)+1, 0, o_); SA2((t_)+1, 1, o_); } \
    BAR(); LGKM0(); MM2(0, 0); MM2(0, 1); BAR(); \
    LDA2(s_, 1); \
    if ((t_)+2 < NT2) { SB2((t_)+2, 0, s_); SB2((t_)+2, 1, s_); } \
    BAR(); LGKM0(); MM2(1, 1); MM2(1, 0); \
    if ((t_)+2 < NT2) { WAITV(4); } else { WAITV(0); } \
    BAR(); }

  for (int t = 0; t < NT2; t += 2) {
    TILE2(t, 0, 1);
    TILE2(t + 1, 1, 0);
  }
  #undef TILE2
  #undef SA2
  #undef SB2
  #undef LDA2
  #undef LDB2
  #undef MM2
  #undef SA1
  #undef SB1
  #undef LDA1
  #undef LDB1
  #undef MM1

  unsigned short* dnp = kh ? dn1 : dn0;
  #pragma unroll
  for (int mf = 0; mf < 8; ++mf) {
    const int rloc = wm + (mf >> 2) * 64 + (mf & 3) * 16 + lg * 4;
    #pragma unroll
    for (int nf = 0; nf < 4; ++nf) {
      f32x4 av = acc[mf][nf];
      int col = n0 + wn4 + nf * 16 + lr;
      #pragma unroll
      for (int q = 0; q < 4; ++q) {
        int r = rloc + q;
        if (m0 + r < cntE)
          dnp[(size_t)(rowbase + m0 + r) * HD + col] = f2bf(av[q]);
      }
    }
  }
}

// ---------------- combine (also computes viol; base inlined from cnt) ----------------
__global__ __launch_bounds__(256) void k_comb(const unsigned short* __restrict__ dn0,
    const unsigned short* __restrict__ dn1,
    const int* __restrict__ cnt, const int* __restrict__ slotrec,
    const float* __restrict__ wts, float* __restrict__ out)
{
  const int t = blockIdx.x;
  const int c = threadIdx.x * 4;
  int cb[NE + 1];
  cb[0] = 0;
  #pragma unroll
  for (int e = 0; e < NE; ++e) cb[e + 1] = cb[e] + cnt[e];
  if (t == 0 && threadIdx.x == 0) {
    int mx = 0;
    #pragma unroll
    for (int e = 0; e < NE; ++e) mx = max(mx, cnt[e]);
    out[(size_t)T_TOK * HD] = (float)mx * (1.f / 1024.f) - 1.f;  // viol
  }
  int r0 = slotrec[t * 2], r1 = slotrec[t * 2 + 1];
  int e0 = r0 >> 16, p0 = r0 & 0xffff;
  int e1 = r1 >> 16, p1 = r1 & 0xffff;
  size_t s0 = (size_t)(cb[e0] + p0) * HD + c;
  size_t s1 = (size_t)(cb[e1] + p1) * HD + c;
  size_t sh = (size_t)(2 * T_TOK + t) * HD + c;
  float w0 = wts[e0 * T_TOK + p0], w1 = wts[e1 * T_TOK + p1];
  u32x2 vs0 = *(const u32x2*)&dn0[sh], vs1 = *(const u32x2*)&dn1[sh];
  u32x2 va0 = *(const u32x2*)&dn0[s0], va1 = *(const u32x2*)&dn1[s0];
  u32x2 vb0 = *(const u32x2*)&dn0[s1], vb1 = *(const u32x2*)&dn1[s1];
  f32x4 o;
  o[0] = (bflo(vs0[0]) + bflo(vs1[0])) + w0 * (bflo(va0[0]) + bflo(va1[0])) + w1 * (bflo(vb0[0]) + bflo(vb1[0]));
  o[1] = (bfhi(vs0[0]) + bfhi(vs1[0])) + w0 * (bfhi(va0[0]) + bfhi(va1[0])) + w1 * (bfhi(vb0[0]) + bfhi(vb1[0]));
  o[2] = (bflo(vs0[1]) + bflo(vs1[1])) + w0 * (bflo(va0[1]) + bflo(va1[1])) + w1 * (bflo(vb0[1]) + bflo(vb1[1]));
  o[3] = (bfhi(vs0[1]) + bfhi(vs1[1])) + w0 * (bfhi(va0[1]) + bfhi(va1[1])) + w1 * (bfhi(vb0[1]) + bfhi(vb1[1]));
  *(f32x4*)&out[(size_t)t * HD + c] = o;
}

extern "C" void kernel_launch(void* const* d_in, const int* in_sizes, int n_in,
                              void* d_out, int out_size, void* d_ws, size_t ws_size,
                              hipStream_t stream)
{
  const float* x    = (const float*)d_in[0];
  const float* gw   = (const float*)d_in[1];
  const float* bias = (const float*)d_in[2];
  const float* Wg   = (const float*)d_in[3];
  const float* Wu   = (const float*)d_in[4];
  const float* Wd   = (const float*)d_in[5];
  const float* Sg   = (const float*)d_in[6];
  const float* Su   = (const float*)d_in[7];
  const float* Sd   = (const float*)d_in[8];
  float* out = (float*)d_out;
  char* ws = (char*)d_ws;

  int*   cnt     = (int*)ws;
  int*   tokens  = (int*)(ws + 512);
  float* wts     = (float*)(ws + 512 + (NE * T_TOK * 4));
  int*   slotrec = (int*)(ws + 512 + 2 * (NE * T_TOK * 4));

  const size_t MB = (size_t)1 << 20;
  unsigned short* xbf = (unsigned short*)(ws + 1 * MB);    // 8 MB
  unsigned short* WdT = (unsigned short*)(ws + 9 * MB);    // 32 MB
  unsigned short* SdT = (unsigned short*)(ws + 41 * MB);   // 4 MB
  unsigned short* Wgu = (unsigned short*)(ws + 45 * MB);   // 64 MB (dead after mlp1)
  unsigned short* Sgu = (unsigned short*)(ws + 109 * MB);  // 8 MB (dead after mlp1)
  unsigned short* actb = (unsigned short*)(ws + 117 * MB); // 48 MB
  unsigned short* dn0 = (unsigned short*)(ws + 45 * MB);   // 24 MB, overlays Wgu
  unsigned short* dn1 = (unsigned short*)(ws + 69 * MB);   // 24 MB, overlays Wgu

  hipMemsetAsync(cnt, 0, 64, stream);
  k_conv<<<dim3(9216 + 256), dim3(256), 0, stream>>>(
      x, gw, bias, Wg, Wu, Sg, Su,
      xbf, Wgu, Sgu, cnt, tokens, wts, slotrec);
  k_mlp1<<<dim3(2304 + 4608), dim3(512), 0, stream>>>(xbf, Wgu, Sgu, Wd, Sd, WdT, SdT, cnt, tokens, actb);
  k_mlp2<<<dim3(1152), dim3(512), 0, stream>>>(actb, WdT, SdT, cnt, dn0, dn1);
  k_comb<<<dim3(T_TOK), dim3(256), 0, stream>>>(dn0, dn1, cnt, slotrec, wts, out);
}